// Round 11
// baseline (89.353 us; speedup 1.0000x reference)
//
#include <hip/hip_runtime.h>
#include <hip/hip_bf16.h>

typedef __bf16 bf16;
typedef __bf16 bf16x4 __attribute__((ext_vector_type(4)));
typedef __bf16 bf16x8 __attribute__((ext_vector_type(8)));
typedef float f32x4 __attribute__((ext_vector_type(4)));

// async global->LDS, 16B per lane. LDS dest must be wave-uniform (HW adds lane*16).
__device__ __forceinline__ void gload16(const void* g, void* l) {
  __builtin_amdgcn_global_load_lds(
      (const __attribute__((address_space(1))) unsigned int*)g,
      (__attribute__((address_space(3))) unsigned int*)l, 16, 0, 0);
}

// Layouts (bf16, BK=64 chunks, 128B rows, swizzle: elem col ^= (row&7)<<3):
//  Pk:    [bh][kb16][row c(256)][64]   (k-dim = l)  row-XOR uses c&7
//  Vt:    [bh][kb4][row l(1024)][64]   (k-dim = c)  row-XOR uses l&7
//  Pattn: [bh][kb4][row c(256)][64]    (k-dim = d)  row-XOR uses c&7

// ---------------- Kernel A: k-projection (x<256) + v-projection (x>=256)
__global__ __launch_bounds__(256) void proj_kv(
    const float* __restrict__ kin, const float* __restrict__ vin,
    const float* __restrict__ wk, const float* __restrict__ bk,
    const float* __restrict__ wv, const float* __restrict__ bv,
    bf16* __restrict__ Pk, bf16* __restrict__ Vt) {
  int b = blockIdx.y;
  int x = blockIdx.x;
  int t = threadIdx.x;
  __shared__ float ch[4288];   // k-path: 4096 linear; v-path: 32*2*67
  if (x < 256) {
    // ---- k projection: LDS-staged channel, broadcast reads, 1KB-coalesced stores
    int g = x;
    {
      const float4* src = reinterpret_cast<const float4*>(kin + ((size_t)b*256 + g)*4096);
      float4* dst4 = reinterpret_cast<float4*>(ch);
#pragma unroll
      for (int i = 0; i < 4; i++) dst4[t + i*256] = src[t + i*256];
    }
    int wave = t >> 6;
    int j = (t >> 3) & 7, n = t & 7;
    float4 wvv = reinterpret_cast<const float4*>(wk)[g*8 + j];
    float bj = bk[g*8 + j];
    __syncthreads();
    int h = g >> 5;
    int c0 = (g & 31)*8;
    int bh = b*8 + h;
#pragma unroll
    for (int p = 0; p < 4; p++) {
      int kb = p*4 + wave;
      int m = kb*2 + (n >> 2);
      int n0 = (n & 3)*8;
      float rr0[16], rr1[16];
      const float4* R0 = reinterpret_cast<const float4*>(ch + (2*m)*64 + 2*n0);
      const float4* R1 = reinterpret_cast<const float4*>(ch + (2*m+1)*64 + 2*n0);
#pragma unroll
      for (int u = 0; u < 4; u++) {
        *reinterpret_cast<float4*>(rr0 + u*4) = R0[u];
        *reinterpret_cast<float4*>(rr1 + u*4) = R1[u];
      }
      bf16x8 o;
#pragma unroll
      for (int u = 0; u < 8; u++)
        o[u] = (bf16)(bj + wvv.x*rr0[2*u] + wvv.y*rr0[2*u+1] + wvv.z*rr1[2*u] + wvv.w*rr1[2*u+1]);
      size_t off = (((size_t)bh*16 + kb)*256 + c0 + j)*64 + (size_t)((n ^ j)*8);
      *reinterpret_cast<bf16x8*>(Pk + off) = o;
    }
  } else {
    // ---- v projection into swizzled chunk-transposed Vt (LDS pad 67: 2-way max)
    int r = x - 256;
    int m = r & 31, h = r >> 5;
    {
      int seg = t >> 2, part = t & 3;
      int gl = seg >> 1, ky = seg & 1;
      const float* src = vin + (((size_t)b*256 + h*32 + gl)*64 + (2*m + ky))*64;
      float* drow = ch + (gl*2 + ky)*67;
#pragma unroll
      for (int i = 0; i < 4; i++) {
        float4 v = reinterpret_cast<const float4*>(src)[part + i*4];
        int x0 = (part + i*4)*4;
        drow[x0]=v.x; drow[x0+1]=v.y; drow[x0+2]=v.z; drow[x0+3]=v.w;
      }
    }
    int cgrp = t & 31, lgr = t >> 5;
    int c0 = cgrp*8;
    float4 wv8[8]; float bb8[8];
#pragma unroll
    for (int u = 0; u < 8; u++) {
      wv8[u] = reinterpret_cast<const float4*>(wv)[h*256 + c0 + u];
      bb8[u] = bv[h*256 + c0 + u];
    }
    __syncthreads();
    const float* r0 = ch + (cgrp*2 + 0)*67;
    const float* r1 = ch + (cgrp*2 + 1)*67;
    int bh = b*8 + h;
    bf16* base = Vt + ((size_t)bh*4 + (c0 >> 6))*1024*64;
    int colx = (c0 & 63) ^ (lgr << 3);
#pragma unroll
    for (int p = 0; p < 4; p++) {
      int n = p*8 + lgr;
      int l = m*32 + n;
      float c00 = r0[2*n], c01 = r0[2*n+1], c10 = r1[2*n], c11 = r1[2*n+1];
      bf16x8 o;
#pragma unroll
      for (int u = 0; u < 8; u++)
        o[u] = (bf16)(bb8[u] + wv8[u].x*c00 + wv8[u].y*c01 + wv8[u].z*c10 + wv8[u].w*c11);
      *reinterpret_cast<bf16x8*>(base + (size_t)l*64 + colx) = o;
    }
  }
}

// ---------------- Kernel B: fused Q-proj + S = Q K^T + softmax -> Pattn.
// BM=64, 256 blocks, 4 waves; wave tile 64c x 64d (32 MFMA/chunk).
// Q conv'd into registers (qreg[16][2], static idx), ds_write'd into the
// double-buffered Q LDS inside the T3/T4 counted-vmcnt pipeline (vmcnt(8)).
__global__ __launch_bounds__(256, 2) void attn_fused(
    const float* __restrict__ qraw, const float* __restrict__ wq,
    const float* __restrict__ bq, const bf16* __restrict__ Pk,
    bf16* __restrict__ Pattn) {
  int raw = blockIdx.x;
  int idx = raw >> 3;
  int bh = (raw & 7)*8 + (idx >> 2);   // 4 c-strips of one bh share an XCD
  int cs = idx & 3;
  int b = bh >> 3, h = bh & 7;
  int t = threadIdx.x, wave = t >> 6, lane = t & 63, lg = lane >> 4, lr = lane & 15;
  __shared__ __attribute__((aligned(16))) char smem[81920];
  bf16* Kb0 = reinterpret_cast<bf16*>(smem);            // 32 KB
  bf16* Kb1 = reinterpret_cast<bf16*>(smem + 32768);    // 32 KB
  bf16* Qb0 = reinterpret_cast<bf16*>(smem + 65536);    //  8 KB
  bf16* Qb1 = reinterpret_cast<bf16*>(smem + 73728);    //  8 KB
  float (*red)[64] = reinterpret_cast<float (*)[64]>(smem + 65536);  // post-loop alias
  bf16* Pst = reinterpret_cast<bf16*>(smem);            // 32 KB post-loop alias
  const char* Kbase = (const char*)Pk + (size_t)bh*524288 + wave*8192 + lane*16;
  char* Kd0 = (char*)Kb0 + wave*8192;  char* Kd1 = (char*)Kb1 + wave*8192;

  // ---- Q-conv prologue into registers.
  // Thread -> row c_local = gg*8 + j (gg = 2*wave + (lane>>5), j = (lane>>2)&7),
  // col-granules (half*4 + nq) for half=0,1 (nq = lane&3). Fully static indexing.
  int gg = 2*wave + (lane >> 5);
  int j  = (lane >> 2) & 7;
  int nq = lane & 3;
  int g  = h*32 + cs*8 + gg;                 // conv group / raw channel
  const float* qch = qraw + ((size_t)b*256 + g)*4096;
  float4 wvq = reinterpret_cast<const float4*>(wq)[g*8 + j];
  float bj = bq[g*8 + j];
  int x0 = nq*16;
  bf16x8 qreg[16][2];
#pragma unroll
  for (int kb = 0; kb < 16; kb++) {
#pragma unroll
    for (int half = 0; half < 2; half++) {
      int y0 = kb*4 + half*2;
      const float4* R0 = reinterpret_cast<const float4*>(qch + y0*64 + x0);
      const float4* R1 = reinterpret_cast<const float4*>(qch + (y0+1)*64 + x0);
      float f0[16], f1[16];
#pragma unroll
      for (int u = 0; u < 4; u++) {
        *reinterpret_cast<float4*>(f0 + u*4) = R0[u];
        *reinterpret_cast<float4*>(f1 + u*4) = R1[u];
      }
      bf16x8 o;
#pragma unroll
      for (int u = 0; u < 8; u++)
        o[u] = (bf16)(bj + wvq.x*f0[2*u] + wvq.y*f0[2*u+1] + wvq.z*f1[2*u] + wvq.w*f1[2*u+1]);
      qreg[kb][half] = o;
    }
  }
  // Q LDS write slots (row-XOR swizzle (row&7)=j on col-granule)
  int qrow = gg*8 + j;
  bf16* qw0a = Qb0 + qrow*64 + ((nq     ^ j)*8);
  bf16* qw0b = Qb0 + qrow*64 + (((4+nq) ^ j)*8);
  bf16* qw1a = Qb1 + qrow*64 + ((nq     ^ j)*8);
  bf16* qw1b = Qb1 + qrow*64 + (((4+nq) ^ j)*8);

#define STAGEK(kb, K_) { \
    const char* kc = Kbase + (size_t)(kb)*32768; \
    _Pragma("unroll") \
    for (int i_ = 0; i_ < 8; i_++) gload16(kc + i_*1024, (K_) + i_*1024); }

  f32x4 acc[4][4];
#pragma unroll
  for (int i = 0; i < 4; i++)
#pragma unroll
    for (int jj = 0; jj < 4; jj++) { f32x4 z = {0.f,0.f,0.f,0.f}; acc[i][jj] = z; }

  // prologue: Q(0) -> Qb0, K(0) staging
  *reinterpret_cast<bf16x8*>(qw0a) = qreg[0][0];
  *reinterpret_cast<bf16x8*>(qw0b) = qreg[0][1];
  STAGEK(0, Kd0);
#pragma unroll
  for (int kb = 0; kb < 16; kb++) {
    if (kb < 15) {
      // stage next chunk (K loads stay in flight across barriers); write next Q
      if (kb & 1) {
        STAGEK(kb+1, Kd0);
        *reinterpret_cast<bf16x8*>(qw0a) = qreg[kb+1][0];
        *reinterpret_cast<bf16x8*>(qw0b) = qreg[kb+1][1];
      } else {
        STAGEK(kb+1, Kd1);
        *reinterpret_cast<bf16x8*>(qw1a) = qreg[kb+1][0];
        *reinterpret_cast<bf16x8*>(qw1b) = qreg[kb+1][1];
      }
      asm volatile("s_waitcnt vmcnt(8) lgkmcnt(0)" ::: "memory");  // prev K done + Q writes done
    } else {
      asm volatile("s_waitcnt vmcnt(0) lgkmcnt(0)" ::: "memory");
    }
    __builtin_amdgcn_s_barrier();
    __builtin_amdgcn_sched_barrier(0);
    const bf16* Kc = (kb & 1) ? Kb1 : Kb0;
    const bf16* Qc = (kb & 1) ? Qb1 : Qb0;
#pragma unroll
    for (int ks = 0; ks < 2; ks++) {
      int colx = (ks*32 + lg*8) ^ ((lr & 7) << 3);
      bf16x8 a[4];
#pragma unroll
      for (int mi = 0; mi < 4; mi++)
        a[mi] = *reinterpret_cast<const bf16x8*>(Qc + (mi*16 + lr)*64 + colx);
#pragma unroll
      for (int ni = 0; ni < 4; ni++) {
        bf16x8 bv2 = *reinterpret_cast<const bf16x8*>(Kc + (wave*64 + ni*16 + lr)*64 + colx);
#pragma unroll
        for (int mi = 0; mi < 4; mi++)
          acc[mi][ni] = __builtin_amdgcn_mfma_f32_16x16x32_bf16(a[mi], bv2, acc[mi][ni], 0, 0, 0);
      }
    }
    __builtin_amdgcn_s_barrier();        // all reads of this buffer done
    __builtin_amdgcn_sched_barrier(0);
  }
#undef STAGEK
  // softmax over d (wave holds 64 d; combine 4 waves via red[4][64])
  const float scale = 0.03125f;
  float sums[4][4];
#pragma unroll
  for (int mi = 0; mi < 4; mi++)
#pragma unroll
    for (int r = 0; r < 4; r++) {
      float mx = fmaxf(fmaxf(acc[mi][0][r], acc[mi][1][r]), fmaxf(acc[mi][2][r], acc[mi][3][r]));
#pragma unroll
      for (int off = 1; off < 16; off <<= 1) mx = fmaxf(mx, __shfl_xor(mx, off, 64));
      red[wave][mi*16 + lg*4 + r] = mx;
    }
  __syncthreads();
#pragma unroll
  for (int mi = 0; mi < 4; mi++)
#pragma unroll
    for (int r = 0; r < 4; r++) {
      int clr = mi*16 + lg*4 + r;
      float mx = fmaxf(fmaxf(red[0][clr], red[1][clr]), fmaxf(red[2][clr], red[3][clr]));
      float s = 0.f;
#pragma unroll
      for (int ni = 0; ni < 4; ni++) {
        float p = __expf(scale*(acc[mi][ni][r] - mx));
        acc[mi][ni][r] = p; s += p;
      }
#pragma unroll
      for (int off = 1; off < 16; off <<= 1) s += __shfl_xor(s, off, 64);
      sums[mi][r] = s;
    }
  __syncthreads();
#pragma unroll
  for (int mi = 0; mi < 4; mi++)
#pragma unroll
    for (int r = 0; r < 4; r++) red[wave][mi*16 + lg*4 + r] = sums[mi][r];
  __syncthreads();
  // normalize + stage P strip into LDS (alias over K buffers) in swizzled layout
#pragma unroll
  for (int mi = 0; mi < 4; mi++)
#pragma unroll
    for (int r = 0; r < 4; r++) {
      int clr = mi*16 + lg*4 + r;
      float iv = 1.f/(red[0][clr] + red[1][clr] + red[2][clr] + red[3][clr]);
#pragma unroll
      for (int ni = 0; ni < 4; ni++) {
        int dl = ni*16 + lr;                     // d within wave's 64-chunk
        Pst[wave*4096 + clr*64 + (dl ^ ((clr & 7) << 3))] = (bf16)(acc[mi][ni][r]*iv);
      }
    }
  __syncthreads();
  // coalesced copy-out: 32 KB total; Pattn chunk kb gets rows cs*64..+64
  const uint4* ls = reinterpret_cast<const uint4*>(Pst);
#pragma unroll
  for (int i = 0; i < 8; i++) {
    int f = i*256 + t;              // 2048 uint4
    int kb = f >> 9, rem = f & 511;
    char* dst = (char*)Pattn + ((size_t)(bh*4 + kb)*256 + cs*64)*128 + (size_t)rem*16;
    *reinterpret_cast<uint4*>(dst) = ls[f];
  }
}

// ---------------- Kernel C: O = Pattn * V (K=256), fused deconv + bias + residual
__global__ __launch_bounds__(256, 4) void pv_deconv(const bf16* __restrict__ Pattn,
    const bf16* __restrict__ Vt, const float* __restrict__ qin,
    const float* __restrict__ wo, const float* __restrict__ bo,
    const float* __restrict__ gamma, float* __restrict__ outp) {
  int raw = blockIdx.x;
  int idx = raw >> 3;
  int pair = (raw & 7)*32 + (idx >> 2);   // (mb,bh); 4 tb-blocks share V chunk + XCD
  int tb = idx & 3;
  int mb = pair & 3, bh = pair >> 2;
  int h = bh & 7, b = bh >> 3;
  int t = threadIdx.x, wave = t >> 6, lane = t & 63, lg = lane >> 4, lr = lane & 15;
  __shared__ __attribute__((aligned(16))) char smem[40960];
  bf16* Pl   = reinterpret_cast<bf16*>(smem);            // 8192 B
  bf16* Vl   = reinterpret_cast<bf16*>(smem + 8192);     // 32768 B
  bf16* OlT  = reinterpret_cast<bf16*>(smem);            // 256*66*2 = 33792 B (post-loop)
  float* wo_s = reinterpret_cast<float*>(smem + 36864);  // 1024 B (post-loop)
  float* bo_s = reinterpret_cast<float*>(smem + 37888);  // 32 B
  const char* Pbase = (const char*)Pattn + ((size_t)bh*4*256 + tb*64)*128;
  const char* Vbase = (const char*)Vt + ((size_t)bh*4*1024 + mb*256)*128;
  f32x4 acc[4][4];
#pragma unroll
  for (int i = 0; i < 4; i++)
#pragma unroll
    for (int j = 0; j < 4; j++) { f32x4 z = {0.f,0.f,0.f,0.f}; acc[i][j] = z; }
  for (int kb = 0; kb < 4; kb++) {
    __syncthreads();
    {
      const char* pc = Pbase + (size_t)kb*32768 + wave*2048 + lane*16;
      char* pl = (char*)Pl + wave*2048;
#pragma unroll
      for (int i = 0; i < 2; i++) gload16(pc + i*1024, pl + i*1024);
      const char* vc = Vbase + (size_t)kb*131072 + wave*8192 + lane*16;
      char* vl = (char*)Vl + wave*8192;
#pragma unroll
      for (int i = 0; i < 8; i++) gload16(vc + i*1024, vl + i*1024);
    }
    __syncthreads();
#pragma unroll
    for (int ks = 0; ks < 2; ks++) {
      int colx = (ks*32 + lg*8) ^ ((lr & 7) << 3);
      bf16x8 a[4];
#pragma unroll
      for (int mi = 0; mi < 4; mi++)
        a[mi] = *reinterpret_cast<const bf16x8*>(Pl + (mi*16 + lr)*64 + colx);
#pragma unroll
      for (int ni = 0; ni < 4; ni++) {
        bf16x8 bv2 = *reinterpret_cast<const bf16x8*>(Vl + (wave*64 + ni*16 + lr)*64 + colx);
#pragma unroll
        for (int mi = 0; mi < 4; mi++)
          acc[mi][ni] = __builtin_amdgcn_mfma_f32_16x16x32_bf16(a[mi], bv2, acc[mi][ni], 0, 0, 0);
      }
    }
  }
  __syncthreads();   // all MFMA LDS reads done before OlT/wo_s overwrite
#pragma unroll
  for (int mi = 0; mi < 4; mi++)
#pragma unroll
    for (int ni = 0; ni < 4; ni++) {
      int l = wave*64 + ni*16 + lr;
      int cb = mi*16 + lg*4;
      bf16x4 p;
      p[0] = (bf16)acc[mi][ni][0]; p[1] = (bf16)acc[mi][ni][1];
      p[2] = (bf16)acc[mi][ni][2]; p[3] = (bf16)acc[mi][ni][3];
      *reinterpret_cast<bf16x4*>(OlT + l*66 + cb) = p;
    }
  wo_s[t] = wo[((size_t)(h*32 + tb*8 + (t>>5)))*32 + (t & 31)];
  if (t < 8) bo_s[t] = bo[h*32 + tb*8 + t];
  __syncthreads();
  // epilogue: deconv 2x2 stride 2 + bias + residual; fully coalesced float4 I/O
  int xq = t & 15, b5 = (t >> 4) & 1, ct = t >> 5;
  float2 wp[8];
#pragma unroll
  for (int j = 0; j < 8; j++)
    wp[j] = *reinterpret_cast<const float2*>(wo_s + ct*32 + j*4 + (1 - b5)*2);
  float bias = bo_s[ct];
  float gm = gamma[0];
  int co = h*32 + tb*8 + ct;
#pragma unroll
  for (int it = 0; it < 8; it++) {
    int y = it*2 + b5;
    int ll0 = it*32 + xq*2;
    bf16x4 o00 = *reinterpret_cast<const bf16x4*>(OlT + ll0*66 + ct*8);
    bf16x4 o01 = *reinterpret_cast<const bf16x4*>(OlT + ll0*66 + ct*8 + 4);
    bf16x4 o10 = *reinterpret_cast<const bf16x4*>(OlT + (ll0+1)*66 + ct*8);
    bf16x4 o11 = *reinterpret_cast<const bf16x4*>(OlT + (ll0+1)*66 + ct*8 + 4);
    float v0 = bias, v1 = bias, v2 = bias, v3 = bias;
#pragma unroll
    for (int j = 0; j < 4; j++) {
      float f0 = (float)o00[j], f1 = (float)o01[j];
      v0 += f0*wp[j].y;   v1 += f0*wp[j].x;
      v0 += f1*wp[4+j].y; v1 += f1*wp[4+j].x;
      float g0 = (float)o10[j], g1 = (float)o11[j];
      v2 += g0*wp[j].y;   v3 += g0*wp[j].x;
      v2 += g1*wp[4+j].y; v3 += g1*wp[4+j].x;
    }
    size_t oi = (((size_t)b*256 + co)*64 + (mb*16 + y))*64 + xq*4;
    float4 qv = *reinterpret_cast<const float4*>(qin + oi);
    float4 ov;
    ov.x = qv.x + gm*v0; ov.y = qv.y + gm*v1;
    ov.z = qv.z + gm*v2; ov.w = qv.w + gm*v3;
    *reinterpret_cast<float4*>(outp + oi) = ov;
  }
}

extern "C" void kernel_launch(void* const* d_in, const int* in_sizes, int n_in,
                              void* d_out, int out_size, void* d_ws, size_t ws_size,
                              hipStream_t stream) {
  const float* q  = (const float*)d_in[0];
  const float* k  = (const float*)d_in[1];
  const float* v  = (const float*)d_in[2];
  const float* wq = (const float*)d_in[3];
  const float* bq = (const float*)d_in[4];
  const float* wk = (const float*)d_in[5];
  const float* bk = (const float*)d_in[6];
  const float* wv = (const float*)d_in[7];
  const float* bv = (const float*)d_in[8];
  const float* wo = (const float*)d_in[9];
  const float* bo = (const float*)d_in[10];
  const float* gamma = (const float*)d_in[11];
  float* out = (float*)d_out;

  char* ws = (char*)d_ws;
  bf16* Pk    = (bf16*)(ws);              //  33,554,432 B
  bf16* Vt    = (bf16*)(ws + 33554432);   //  33,554,432 B
  bf16* Pattn = (bf16*)(ws + 67108864);   //   8,388,608 B

  proj_kv  <<<dim3(512, 8), 256, 0, stream>>>(k, v, wk, bk, wv, bv, Pk, Vt);
  attn_fused<<<dim3(256), 256, 0, stream>>>(q, wq, bq, Pk, Pattn);
  pv_deconv<<<dim3(1024), 256, 0, stream>>>(Pattn, Vt, q, wo, bo, gamma, out);
}

// Round 12
// 86.661 us; speedup vs baseline: 1.0311x; 1.0311x over previous
//
#include <hip/hip_runtime.h>
#include <hip/hip_bf16.h>

typedef __bf16 bf16;
typedef __bf16 bf16x4 __attribute__((ext_vector_type(4)));
typedef __bf16 bf16x8 __attribute__((ext_vector_type(8)));
typedef float f32x4 __attribute__((ext_vector_type(4)));

// async global->LDS, 16B per lane. LDS dest must be wave-uniform (HW adds lane*16).
__device__ __forceinline__ void gload16(const void* g, void* l) {
  __builtin_amdgcn_global_load_lds(
      (const __attribute__((address_space(1))) unsigned int*)g,
      (__attribute__((address_space(3))) unsigned int*)l, 16, 0, 0);
}

// Layouts (bf16, BK=64 chunks, 128B rows, swizzle: elem col ^= (row&7)<<3):
//  Pk:    [bh][kb16][row c(256)][64]   (k-dim = l)  row-XOR uses c&7
//  Vt:    [bh][kb4][row l(1024)][64]   (k-dim = c)  row-XOR uses l&7
//  Pattn: [bh][kb4][row c(256)][64]    (k-dim = d)  row-XOR uses c&7

// ---------------- Kernel A: k-projection (x<256) + v-projection (x>=256)
__global__ __launch_bounds__(256) void proj_kv(
    const float* __restrict__ kin, const float* __restrict__ vin,
    const float* __restrict__ wk, const float* __restrict__ bk,
    const float* __restrict__ wv, const float* __restrict__ bv,
    bf16* __restrict__ Pk, bf16* __restrict__ Vt) {
  int b = blockIdx.y;
  int x = blockIdx.x;
  int t = threadIdx.x;
  __shared__ float ch[4288];   // k-path: 4096 linear; v-path: 32*2*67
  if (x < 256) {
    // ---- k projection: LDS-staged channel, broadcast reads, 1KB-coalesced stores
    int g = x;
    {
      const float4* src = reinterpret_cast<const float4*>(kin + ((size_t)b*256 + g)*4096);
      float4* dst4 = reinterpret_cast<float4*>(ch);
#pragma unroll
      for (int i = 0; i < 4; i++) dst4[t + i*256] = src[t + i*256];
    }
    int wave = t >> 6;
    int j = (t >> 3) & 7, n = t & 7;
    float4 wvv = reinterpret_cast<const float4*>(wk)[g*8 + j];
    float bj = bk[g*8 + j];
    __syncthreads();
    int h = g >> 5;
    int c0 = (g & 31)*8;
    int bh = b*8 + h;
#pragma unroll
    for (int p = 0; p < 4; p++) {
      int kb = p*4 + wave;
      int m = kb*2 + (n >> 2);
      int n0 = (n & 3)*8;
      float rr0[16], rr1[16];
      const float4* R0 = reinterpret_cast<const float4*>(ch + (2*m)*64 + 2*n0);
      const float4* R1 = reinterpret_cast<const float4*>(ch + (2*m+1)*64 + 2*n0);
#pragma unroll
      for (int u = 0; u < 4; u++) {
        *reinterpret_cast<float4*>(rr0 + u*4) = R0[u];
        *reinterpret_cast<float4*>(rr1 + u*4) = R1[u];
      }
      bf16x8 o;
#pragma unroll
      for (int u = 0; u < 8; u++)
        o[u] = (bf16)(bj + wvv.x*rr0[2*u] + wvv.y*rr0[2*u+1] + wvv.z*rr1[2*u] + wvv.w*rr1[2*u+1]);
      size_t off = (((size_t)bh*16 + kb)*256 + c0 + j)*64 + (size_t)((n ^ j)*8);
      *reinterpret_cast<bf16x8*>(Pk + off) = o;
    }
  } else {
    // ---- v projection into swizzled chunk-transposed Vt (LDS pad 67: 2-way max)
    int r = x - 256;
    int m = r & 31, h = r >> 5;
    {
      int seg = t >> 2, part = t & 3;
      int gl = seg >> 1, ky = seg & 1;
      const float* src = vin + (((size_t)b*256 + h*32 + gl)*64 + (2*m + ky))*64;
      float* drow = ch + (gl*2 + ky)*67;
#pragma unroll
      for (int i = 0; i < 4; i++) {
        float4 v = reinterpret_cast<const float4*>(src)[part + i*4];
        int x0 = (part + i*4)*4;
        drow[x0]=v.x; drow[x0+1]=v.y; drow[x0+2]=v.z; drow[x0+3]=v.w;
      }
    }
    int cgrp = t & 31, lgr = t >> 5;
    int c0 = cgrp*8;
    float4 wv8[8]; float bb8[8];
#pragma unroll
    for (int u = 0; u < 8; u++) {
      wv8[u] = reinterpret_cast<const float4*>(wv)[h*256 + c0 + u];
      bb8[u] = bv[h*256 + c0 + u];
    }
    __syncthreads();
    const float* r0 = ch + (cgrp*2 + 0)*67;
    const float* r1 = ch + (cgrp*2 + 1)*67;
    int bh = b*8 + h;
    bf16* base = Vt + ((size_t)bh*4 + (c0 >> 6))*1024*64;
    int colx = (c0 & 63) ^ (lgr << 3);
#pragma unroll
    for (int p = 0; p < 4; p++) {
      int n = p*8 + lgr;
      int l = m*32 + n;
      float c00 = r0[2*n], c01 = r0[2*n+1], c10 = r1[2*n], c11 = r1[2*n+1];
      bf16x8 o;
#pragma unroll
      for (int u = 0; u < 8; u++)
        o[u] = (bf16)(bb8[u] + wv8[u].x*c00 + wv8[u].y*c01 + wv8[u].z*c10 + wv8[u].w*c11);
      *reinterpret_cast<bf16x8*>(base + (size_t)l*64 + colx) = o;
    }
  }
}

// ---------------- Kernel B: fused Q-proj (LDS-pipelined conv) + S=QK^T + softmax.
// 256 blocks, 4 waves; wave tile 64c x 64d.  Per iteration:
//   stage raw q[kb+2] (2 gload16) + K[kb+1] (8 gload16) -> vmcnt(10) -> barrier
//   -> conv q[kb+1] from raw LDS (overlaps MFMA) ; MFMA chunk kb -> lgkm0 -> barrier
__global__ __launch_bounds__(256) void attn_fused(
    const float* __restrict__ qraw, const float* __restrict__ wq,
    const float* __restrict__ bq, const bf16* __restrict__ Pk,
    bf16* __restrict__ Pattn) {
  int raw = blockIdx.x;
  int idx = raw >> 3;
  int bh = (raw & 7)*8 + (idx >> 2);   // 4 c-strips of one bh share an XCD
  int cs = idx & 3;
  int b = bh >> 3, h = bh & 7;
  int t = threadIdx.x, wave = t >> 6, lane = t & 63, lg = lane >> 4, lr = lane & 15;
  __shared__ __attribute__((aligned(16))) char smem[99328];
  bf16* Kb0 = reinterpret_cast<bf16*>(smem);            // 32 KB
  bf16* Kb1 = reinterpret_cast<bf16*>(smem + 32768);    // 32 KB
  bf16* Qb0 = reinterpret_cast<bf16*>(smem + 65536);    //  8 KB
  bf16* Qb1 = reinterpret_cast<bf16*>(smem + 73728);    //  8 KB
  char* rb0 = smem + 81920;                             //  8704 B raw q (8ch x 1088)
  char* rb1 = smem + 90624;                             //  8704 B
  float (*red)[64] = reinterpret_cast<float (*)[64]>(smem + 65536);  // post-loop alias
  bf16* Pst = reinterpret_cast<bf16*>(smem);            // 32 KB post-loop alias
  const char* Kbase = (const char*)Pk + (size_t)bh*524288 + wave*8192 + lane*16;
  char* Kd0 = (char*)Kb0 + wave*8192;  char* Kd1 = (char*)Kb1 + wave*8192;

  // raw q: wave stages its 2 channels; chunk kb = 1KB contiguous per channel
  const char* qchb = (const char*)(qraw + ((size_t)b*256 + h*32 + cs*8 + 2*wave)*4096) + lane*16;
  // conv mapping: thread -> row c_local = t>>2, granule pair {nq, nq+4}
  int c_local = t >> 2, nq = t & 3;
  int chq = c_local >> 3, jq = c_local & 7;
  int gfull = h*32 + cs*8 + chq;
  float4 wvq = reinterpret_cast<const float4*>(wq)[gfull*8 + jq];
  float bjq = bq[gfull*8 + jq];

#define STAGEK(kb, K_) { \
    const char* kc = Kbase + (size_t)(kb)*32768; \
    _Pragma("unroll") \
    for (int i_ = 0; i_ < 8; i_++) gload16(kc + i_*1024, (K_) + i_*1024); }

#define STAGERAW(ct, rbp) { \
    const char* s_ = qchb + (size_t)(ct)*1024; \
    gload16(s_,         (rbp) + 2*wave*1088); \
    gload16(s_ + 16384, (rbp) + 2*wave*1088 + 1088); }

#define CONVQ(rbp, Qd) { \
    const char* rbase = (rbp) + chq*1088 + nq*64; \
    float f0_[16], f1_[16]; \
    _Pragma("unroll") \
    for (int k_ = 0; k_ < 4; k_++) { \
      *reinterpret_cast<float4*>(f0_ + 4*k_) = *reinterpret_cast<const float4*>(rbase + k_*16); \
      *reinterpret_cast<float4*>(f1_ + 4*k_) = *reinterpret_cast<const float4*>(rbase + 256 + k_*16); } \
    bf16x8 o0_; \
    _Pragma("unroll") \
    for (int u_ = 0; u_ < 8; u_++) \
      o0_[u_] = (bf16)(bjq + wvq.x*f0_[2*u_] + wvq.y*f0_[2*u_+1] + wvq.z*f1_[2*u_] + wvq.w*f1_[2*u_+1]); \
    *reinterpret_cast<bf16x8*>((Qd) + c_local*64 + ((nq ^ jq)*8)) = o0_; \
    _Pragma("unroll") \
    for (int k_ = 0; k_ < 4; k_++) { \
      *reinterpret_cast<float4*>(f0_ + 4*k_) = *reinterpret_cast<const float4*>(rbase + 512 + k_*16); \
      *reinterpret_cast<float4*>(f1_ + 4*k_) = *reinterpret_cast<const float4*>(rbase + 768 + k_*16); } \
    bf16x8 o1_; \
    _Pragma("unroll") \
    for (int u_ = 0; u_ < 8; u_++) \
      o1_[u_] = (bf16)(bjq + wvq.x*f0_[2*u_] + wvq.y*f0_[2*u_+1] + wvq.z*f1_[2*u_] + wvq.w*f1_[2*u_+1]); \
    *reinterpret_cast<bf16x8*>((Qd) + c_local*64 + (((nq + 4) ^ jq)*8)) = o1_; }

  f32x4 acc[4][4];
#pragma unroll
  for (int i = 0; i < 4; i++)
#pragma unroll
    for (int jj = 0; jj < 4; jj++) { f32x4 z = {0.f,0.f,0.f,0.f}; acc[i][jj] = z; }

  // prologue: raw[0]->rb0, raw[1]->rb1, K[0]; conv Q[0] once raw[0] lands
  STAGERAW(0, rb0);
  STAGERAW(1, rb1);
  STAGEK(0, Kd0);
  asm volatile("s_waitcnt vmcnt(10)" ::: "memory");   // raw[0] complete
  CONVQ(rb0, Qb0);
  asm volatile("s_waitcnt lgkmcnt(0)" ::: "memory");  // Q[0] writes drained
#pragma unroll
  for (int kb = 0; kb < 16; kb++) {
    if (kb <= 13) { STAGERAW(kb + 2, (kb & 1) ? rb1 : rb0); }
    if (kb <= 14) { if (kb & 1) { STAGEK(kb + 1, Kd0); } else { STAGEK(kb + 1, Kd1); } }
    if (kb <= 13)      asm volatile("s_waitcnt vmcnt(10)" ::: "memory");
    else if (kb == 14) asm volatile("s_waitcnt vmcnt(8)" ::: "memory");
    else               asm volatile("s_waitcnt vmcnt(0)" ::: "memory");
    __builtin_amdgcn_s_barrier();        // Q[kb] + K[kb] visible to all waves
    __builtin_amdgcn_sched_barrier(0);
    // conv next chunk's Q (reads own-wave raw, writes inactive Q buffer);
    // overlaps the MFMA below (separate pipes, different buffers)
    if (kb <= 14) {
      if (kb & 1) { CONVQ(rb0, Qb0); } else { CONVQ(rb1, Qb1); }
    }
    const bf16* Kc = (kb & 1) ? Kb1 : Kb0;
    const bf16* Qc = (kb & 1) ? Qb1 : Qb0;
#pragma unroll
    for (int ks = 0; ks < 2; ks++) {
      int colx = (ks*32 + lg*8) ^ ((lr & 7) << 3);
      bf16x8 a[4];
#pragma unroll
      for (int mi = 0; mi < 4; mi++)
        a[mi] = *reinterpret_cast<const bf16x8*>(Qc + (mi*16 + lr)*64 + colx);
#pragma unroll
      for (int ni = 0; ni < 4; ni++) {
        bf16x8 bv2 = *reinterpret_cast<const bf16x8*>(Kc + (wave*64 + ni*16 + lr)*64 + colx);
#pragma unroll
        for (int mi = 0; mi < 4; mi++)
          acc[mi][ni] = __builtin_amdgcn_mfma_f32_16x16x32_bf16(a[mi], bv2, acc[mi][ni], 0, 0, 0);
      }
    }
    asm volatile("s_waitcnt lgkmcnt(0)" ::: "memory");  // conv writes + MFMA reads done
    __builtin_amdgcn_s_barrier();
    __builtin_amdgcn_sched_barrier(0);
  }
#undef STAGEK
#undef STAGERAW
#undef CONVQ
  // softmax over d (wave holds 64 d; combine 4 waves via red[4][64])
  const float scale = 0.03125f;
  float sums[4][4];
#pragma unroll
  for (int mi = 0; mi < 4; mi++)
#pragma unroll
    for (int r = 0; r < 4; r++) {
      float mx = fmaxf(fmaxf(acc[mi][0][r], acc[mi][1][r]), fmaxf(acc[mi][2][r], acc[mi][3][r]));
#pragma unroll
      for (int off = 1; off < 16; off <<= 1) mx = fmaxf(mx, __shfl_xor(mx, off, 64));
      red[wave][mi*16 + lg*4 + r] = mx;
    }
  __syncthreads();
#pragma unroll
  for (int mi = 0; mi < 4; mi++)
#pragma unroll
    for (int r = 0; r < 4; r++) {
      int clr = mi*16 + lg*4 + r;
      float mx = fmaxf(fmaxf(red[0][clr], red[1][clr]), fmaxf(red[2][clr], red[3][clr]));
      float s = 0.f;
#pragma unroll
      for (int ni = 0; ni < 4; ni++) {
        float p = __expf(scale*(acc[mi][ni][r] - mx));
        acc[mi][ni][r] = p; s += p;
      }
#pragma unroll
      for (int off = 1; off < 16; off <<= 1) s += __shfl_xor(s, off, 64);
      sums[mi][r] = s;
    }
  __syncthreads();
#pragma unroll
  for (int mi = 0; mi < 4; mi++)
#pragma unroll
    for (int r = 0; r < 4; r++) red[wave][mi*16 + lg*4 + r] = sums[mi][r];
  __syncthreads();
  // normalize + stage P strip into LDS (alias over K buffers) in swizzled layout
#pragma unroll
  for (int mi = 0; mi < 4; mi++)
#pragma unroll
    for (int r = 0; r < 4; r++) {
      int clr = mi*16 + lg*4 + r;
      float iv = 1.f/(red[0][clr] + red[1][clr] + red[2][clr] + red[3][clr]);
#pragma unroll
      for (int ni = 0; ni < 4; ni++) {
        int dl = ni*16 + lr;                     // d within wave's 64-chunk
        Pst[wave*4096 + clr*64 + (dl ^ ((clr & 7) << 3))] = (bf16)(acc[mi][ni][r]*iv);
      }
    }
  __syncthreads();
  // coalesced copy-out: 32 KB total; Pattn chunk kb gets rows cs*64..+64
  const uint4* ls = reinterpret_cast<const uint4*>(Pst);
#pragma unroll
  for (int i = 0; i < 8; i++) {
    int f = i*256 + t;              // 2048 uint4
    int kb = f >> 9, rem = f & 511;
    char* dst = (char*)Pattn + ((size_t)(bh*4 + kb)*256 + cs*64)*128 + (size_t)rem*16;
    *reinterpret_cast<uint4*>(dst) = ls[f];
  }
}

// ---------------- Kernel C: O = Pattn * V (K=256), fused deconv + bias + residual
__global__ __launch_bounds__(256, 4) void pv_deconv(const bf16* __restrict__ Pattn,
    const bf16* __restrict__ Vt, const float* __restrict__ qin,
    const float* __restrict__ wo, const float* __restrict__ bo,
    const float* __restrict__ gamma, float* __restrict__ outp) {
  int raw = blockIdx.x;
  int idx = raw >> 3;
  int pair = (raw & 7)*32 + (idx >> 2);   // (mb,bh); 4 tb-blocks share V chunk + XCD
  int tb = idx & 3;
  int mb = pair & 3, bh = pair >> 2;
  int h = bh & 7, b = bh >> 3;
  int t = threadIdx.x, wave = t >> 6, lane = t & 63, lg = lane >> 4, lr = lane & 15;
  __shared__ __attribute__((aligned(16))) char smem[40960];
  bf16* Pl   = reinterpret_cast<bf16*>(smem);            // 8192 B
  bf16* Vl   = reinterpret_cast<bf16*>(smem + 8192);     // 32768 B
  bf16* OlT  = reinterpret_cast<bf16*>(smem);            // 256*66*2 = 33792 B (post-loop)
  float* wo_s = reinterpret_cast<float*>(smem + 36864);  // 1024 B (post-loop)
  float* bo_s = reinterpret_cast<float*>(smem + 37888);  // 32 B
  const char* Pbase = (const char*)Pattn + ((size_t)bh*4*256 + tb*64)*128;
  const char* Vbase = (const char*)Vt + ((size_t)bh*4*1024 + mb*256)*128;
  f32x4 acc[4][4];
#pragma unroll
  for (int i = 0; i < 4; i++)
#pragma unroll
    for (int j = 0; j < 4; j++) { f32x4 z = {0.f,0.f,0.f,0.f}; acc[i][j] = z; }
  for (int kb = 0; kb < 4; kb++) {
    __syncthreads();
    {
      const char* pc = Pbase + (size_t)kb*32768 + wave*2048 + lane*16;
      char* pl = (char*)Pl + wave*2048;
#pragma unroll
      for (int i = 0; i < 2; i++) gload16(pc + i*1024, pl + i*1024);
      const char* vc = Vbase + (size_t)kb*131072 + wave*8192 + lane*16;
      char* vl = (char*)Vl + wave*8192;
#pragma unroll
      for (int i = 0; i < 8; i++) gload16(vc + i*1024, vl + i*1024);
    }
    __syncthreads();
#pragma unroll
    for (int ks = 0; ks < 2; ks++) {
      int colx = (ks*32 + lg*8) ^ ((lr & 7) << 3);
      bf16x8 a[4];
#pragma unroll
      for (int mi = 0; mi < 4; mi++)
        a[mi] = *reinterpret_cast<const bf16x8*>(Pl + (mi*16 + lr)*64 + colx);
#pragma unroll
      for (int ni = 0; ni < 4; ni++) {
        bf16x8 bv2 = *reinterpret_cast<const bf16x8*>(Vl + (wave*64 + ni*16 + lr)*64 + colx);
#pragma unroll
        for (int mi = 0; mi < 4; mi++)
          acc[mi][ni] = __builtin_amdgcn_mfma_f32_16x16x32_bf16(a[mi], bv2, acc[mi][ni], 0, 0, 0);
      }
    }
  }
  __syncthreads();   // all MFMA LDS reads done before OlT/wo_s overwrite
#pragma unroll
  for (int mi = 0; mi < 4; mi++)
#pragma unroll
    for (int ni = 0; ni < 4; ni++) {
      int l = wave*64 + ni*16 + lr;
      int cb = mi*16 + lg*4;
      bf16x4 p;
      p[0] = (bf16)acc[mi][ni][0]; p[1] = (bf16)acc[mi][ni][1];
      p[2] = (bf16)acc[mi][ni][2]; p[3] = (bf16)acc[mi][ni][3];
      *reinterpret_cast<bf16x4*>(OlT + l*66 + cb) = p;
    }
  wo_s[t] = wo[((size_t)(h*32 + tb*8 + (t>>5)))*32 + (t & 31)];
  if (t < 8) bo_s[t] = bo[h*32 + tb*8 + t];
  __syncthreads();
  // epilogue: deconv 2x2 stride 2 + bias + residual; fully coalesced float4 I/O
  int xq = t & 15, b5 = (t >> 4) & 1, ct = t >> 5;
  float2 wp[8];
#pragma unroll
  for (int j = 0; j < 8; j++)
    wp[j] = *reinterpret_cast<const float2*>(wo_s + ct*32 + j*4 + (1 - b5)*2);
  float bias = bo_s[ct];
  float gm = gamma[0];
  int co = h*32 + tb*8 + ct;
#pragma unroll
  for (int it = 0; it < 8; it++) {
    int y = it*2 + b5;
    int ll0 = it*32 + xq*2;
    bf16x4 o00 = *reinterpret_cast<const bf16x4*>(OlT + ll0*66 + ct*8);
    bf16x4 o01 = *reinterpret_cast<const bf16x4*>(OlT + ll0*66 + ct*8 + 4);
    bf16x4 o10 = *reinterpret_cast<const bf16x4*>(OlT + (ll0+1)*66 + ct*8);
    bf16x4 o11 = *reinterpret_cast<const bf16x4*>(OlT + (ll0+1)*66 + ct*8 + 4);
    float v0 = bias, v1 = bias, v2 = bias, v3 = bias;
#pragma unroll
    for (int j = 0; j < 4; j++) {
      float f0 = (float)o00[j], f1 = (float)o01[j];
      v0 += f0*wp[j].y;   v1 += f0*wp[j].x;
      v0 += f1*wp[4+j].y; v1 += f1*wp[4+j].x;
      float g0 = (float)o10[j], g1 = (float)o11[j];
      v2 += g0*wp[j].y;   v3 += g0*wp[j].x;
      v2 += g1*wp[4+j].y; v3 += g1*wp[4+j].x;
    }
    size_t oi = (((size_t)b*256 + co)*64 + (mb*16 + y))*64 + xq*4;
    float4 qv = *reinterpret_cast<const float4*>(qin + oi);
    float4 ov;
    ov.x = qv.x + gm*v0; ov.y = qv.y + gm*v1;
    ov.z = qv.z + gm*v2; ov.w = qv.w + gm*v3;
    *reinterpret_cast<float4*>(outp + oi) = ov;
  }
}

extern "C" void kernel_launch(void* const* d_in, const int* in_sizes, int n_in,
                              void* d_out, int out_size, void* d_ws, size_t ws_size,
                              hipStream_t stream) {
  const float* q  = (const float*)d_in[0];
  const float* k  = (const float*)d_in[1];
  const float* v  = (const float*)d_in[2];
  const float* wq = (const float*)d_in[3];
  const float* bq = (const float*)d_in[4];
  const float* wk = (const float*)d_in[5];
  const float* bk = (const float*)d_in[6];
  const float* wv = (const float*)d_in[7];
  const float* bv = (const float*)d_in[8];
  const float* wo = (const float*)d_in[9];
  const float* bo = (const float*)d_in[10];
  const float* gamma = (const float*)d_in[11];
  float* out = (float*)d_out;

  char* ws = (char*)d_ws;
  bf16* Pk    = (bf16*)(ws);              //  33,554,432 B
  bf16* Vt    = (bf16*)(ws + 33554432);   //  33,554,432 B
  bf16* Pattn = (bf16*)(ws + 67108864);   //   8,388,608 B

  proj_kv  <<<dim3(512, 8), 256, 0, stream>>>(k, v, wk, bk, wv, bv, Pk, Vt);
  attn_fused<<<dim3(256), 256, 0, stream>>>(q, wq, bq, Pk, Pattn);
  pv_deconv<<<dim3(1024), 256, 0, stream>>>(Pattn, Vt, q, wo, bo, gamma, out);
}

// Round 13
// 80.518 us; speedup vs baseline: 1.1097x; 1.0763x over previous
//
#include <hip/hip_runtime.h>
#include <hip/hip_bf16.h>

typedef __bf16 bf16;
typedef __bf16 bf16x4 __attribute__((ext_vector_type(4)));
typedef __bf16 bf16x8 __attribute__((ext_vector_type(8)));
typedef float f32x4 __attribute__((ext_vector_type(4)));

// async global->LDS, 16B per lane. LDS dest must be wave-uniform (HW adds lane*16).
__device__ __forceinline__ void gload16(const void* g, void* l) {
  __builtin_amdgcn_global_load_lds(
      (const __attribute__((address_space(1))) unsigned int*)g,
      (__attribute__((address_space(3))) unsigned int*)l, 16, 0, 0);
}

// Layouts (bf16, BK=64 chunks, 128B rows, swizzle: elem col ^= (row&7)<<3):
//  Pq/Pk: [bh][kb16][row c(256)][64]   (k-dim = l)  row-XOR uses c&7
//  Vt:    [bh][kb4][row l(1024)][64]   (k-dim = c)  row-XOR uses l&7
//  Pattn: [bh][kb4][row c(256)][64]    (k-dim = d)  row-XOR uses c&7

// ---------------- Kernel A: projections. x<128: k-pair, x<256: q-pair, else v.
// k/q path: 2 channels per block, both staged up-front via gload16 into LDS dbuf,
// counted vmcnt(4) (never 0) so ch1 loads / ch0 stores stay in flight.
__global__ __launch_bounds__(256) void proj_kqv(
    const float* __restrict__ kin, const float* __restrict__ qin,
    const float* __restrict__ vin,
    const float* __restrict__ wk, const float* __restrict__ bk,
    const float* __restrict__ wq, const float* __restrict__ bq,
    const float* __restrict__ wv, const float* __restrict__ bv,
    bf16* __restrict__ Pk, bf16* __restrict__ Pq, bf16* __restrict__ Vt) {
  int b = blockIdx.y;
  int x = blockIdx.x;
  int t = threadIdx.x;
  int wave = t >> 6, lane = t & 63;
  __shared__ __attribute__((aligned(16))) char smem[32768];
  if (x < 256) {
    bool isq = x >= 128;
    int g0 = (x & 127)*2;
    const float* in   = isq ? qin : kin;
    const float* w    = isq ? wq : wk;
    const float* bias = isq ? bq : bk;
    bf16* out         = isq ? Pq : Pk;
    int j = (t >> 3) & 7, n = t & 7;
    // weights FIRST (program order matters for FIFO vmcnt accounting)
    float4 wv0 = reinterpret_cast<const float4*>(w)[g0*8 + j];
    float  bb0 = bias[g0*8 + j];
    float4 wv1 = reinterpret_cast<const float4*>(w)[g0*8 + 8 + j];
    float  bb1 = bias[g0*8 + 8 + j];
    __builtin_amdgcn_sched_barrier(0);
    const char* s0 = (const char*)(in + ((size_t)b*256 + g0)*4096) + wave*4096 + lane*16;
    char* d0 = smem + wave*4096;
    char* d1 = smem + 16384 + wave*4096;
#pragma unroll
    for (int i = 0; i < 4; i++) gload16(s0 + i*1024, d0 + i*1024);
    __builtin_amdgcn_sched_barrier(0);
#pragma unroll
    for (int i = 0; i < 4; i++) gload16(s0 + 16384 + i*1024, d1 + i*1024);
    __builtin_amdgcn_sched_barrier(0);
    int h = g0 >> 5;                 // g0 even -> g0+1 shares h
    int bh = b*8 + h;

#define CONVST(bufp, g, wvv, bj) { \
    const float* chf = reinterpret_cast<const float*>(bufp); \
    int c0l = ((g) & 31)*8; \
    _Pragma("unroll") \
    for (int p = 0; p < 4; p++) { \
      int kb = p*4 + wave; \
      int m = kb*2 + (n >> 2); \
      int n0 = (n & 3)*8; \
      float rr0[16], rr1[16]; \
      const float4* R0 = reinterpret_cast<const float4*>(chf + (2*m)*64 + 2*n0); \
      const float4* R1 = reinterpret_cast<const float4*>(chf + (2*m+1)*64 + 2*n0); \
      _Pragma("unroll") \
      for (int u = 0; u < 4; u++) { \
        *reinterpret_cast<float4*>(rr0 + u*4) = R0[u]; \
        *reinterpret_cast<float4*>(rr1 + u*4) = R1[u]; \
      } \
      bf16x8 o; \
      _Pragma("unroll") \
      for (int u = 0; u < 8; u++) \
        o[u] = (bf16)((bj) + (wvv).x*rr0[2*u] + (wvv).y*rr0[2*u+1] + (wvv).z*rr1[2*u] + (wvv).w*rr1[2*u+1]); \
      size_t off = (((size_t)bh*16 + kb)*256 + c0l + j)*64 + (size_t)((n ^ j)*8); \
      *reinterpret_cast<bf16x8*>(out + off) = o; \
    } }

    asm volatile("s_waitcnt vmcnt(4)" ::: "memory");   // weights + ch0 loads done
    __builtin_amdgcn_s_barrier();
    CONVST(smem, g0, wv0, bb0);                         // 4 stores issued
    __builtin_amdgcn_sched_barrier(0);
    asm volatile("s_waitcnt vmcnt(4)" ::: "memory");   // ch1 loads done; stores in flight
    __builtin_amdgcn_s_barrier();
    CONVST(smem + 16384, g0 + 1, wv1, bb1);
#undef CONVST
  } else {
    // ---- v projection into swizzled chunk-transposed Vt (pad 67: 2-way max)
    float* ch = reinterpret_cast<float*>(smem);
    int r = x - 256;
    int m = r & 31, h = r >> 5;
    {
      int seg = t >> 2, part = t & 3;
      int gl = seg >> 1, ky = seg & 1;
      const float* src = vin + (((size_t)b*256 + h*32 + gl)*64 + (2*m + ky))*64;
      float* drow = ch + (gl*2 + ky)*67;
#pragma unroll
      for (int i = 0; i < 4; i++) {
        float4 v = reinterpret_cast<const float4*>(src)[part + i*4];
        int x0 = (part + i*4)*4;
        drow[x0]=v.x; drow[x0+1]=v.y; drow[x0+2]=v.z; drow[x0+3]=v.w;
      }
    }
    int cgrp = t & 31, lgr = t >> 5;
    int c0 = cgrp*8;
    float4 wv8[8]; float bb8[8];
#pragma unroll
    for (int u = 0; u < 8; u++) {
      wv8[u] = reinterpret_cast<const float4*>(wv)[h*256 + c0 + u];
      bb8[u] = bv[h*256 + c0 + u];
    }
    __syncthreads();
    const float* r0 = ch + (cgrp*2 + 0)*67;
    const float* r1 = ch + (cgrp*2 + 1)*67;
    int bh = b*8 + h;
    bf16* base = Vt + ((size_t)bh*4 + (c0 >> 6))*1024*64;
    int colx = (c0 & 63) ^ (lgr << 3);
#pragma unroll
    for (int p = 0; p < 4; p++) {
      int n = p*8 + lgr;
      int l = m*32 + n;
      float c00 = r0[2*n], c01 = r0[2*n+1], c10 = r1[2*n], c11 = r1[2*n+1];
      bf16x8 o;
#pragma unroll
      for (int u = 0; u < 8; u++)
        o[u] = (bf16)(bb8[u] + wv8[u].x*c00 + wv8[u].y*c01 + wv8[u].z*c10 + wv8[u].w*c11);
      *reinterpret_cast<bf16x8*>(base + (size_t)l*64 + colx) = o;
    }
  }
}

// ---------------- Kernel B: S = Q K^T + softmax -> Pattn.  BM=64, 256 blocks,
// 4 waves; wave tile 64c x 64d (4x4 frags, 32 MFMA/chunk).  T3/T4 2-phase
// counted-vmcnt pipeline: K+Q double-buffered LDS via gload16, vmcnt(10) never 0.
__global__ __launch_bounds__(256, 2) void attn_qk(
    const bf16* __restrict__ Pq, const bf16* __restrict__ Pk,
    bf16* __restrict__ Pattn) {
  int raw = blockIdx.x;
  int idx = raw >> 3;
  int bh = (raw & 7)*8 + (idx >> 2);   // 4 c-strips of one bh share an XCD
  int cs = idx & 3;
  int t = threadIdx.x, wave = t >> 6, lane = t & 63, lg = lane >> 4, lr = lane & 15;
  __shared__ __attribute__((aligned(16))) char smem[81920];
  bf16* Kb0 = reinterpret_cast<bf16*>(smem);            // 32 KB
  bf16* Kb1 = reinterpret_cast<bf16*>(smem + 32768);    // 32 KB
  bf16* Qb0 = reinterpret_cast<bf16*>(smem + 65536);    //  8 KB
  bf16* Qb1 = reinterpret_cast<bf16*>(smem + 73728);    //  8 KB
  float (*red)[64] = reinterpret_cast<float (*)[64]>(smem + 65536);  // post-loop alias
  bf16* Pst = reinterpret_cast<bf16*>(smem);            // 32 KB post-loop alias
  const char* Kbase = (const char*)Pk + (size_t)bh*524288 + wave*8192 + lane*16;
  const char* Qbase = (const char*)Pq + (size_t)bh*524288 + (size_t)cs*8192 + wave*2048 + lane*16;
  char* Kd0 = (char*)Kb0 + wave*8192;  char* Kd1 = (char*)Kb1 + wave*8192;
  char* Qd0 = (char*)Qb0 + wave*2048;  char* Qd1 = (char*)Qb1 + wave*2048;

#define STAGE(kb, K_, Q_) { \
    const char* kc = Kbase + (size_t)(kb)*32768; \
    _Pragma("unroll") \
    for (int i_ = 0; i_ < 8; i_++) gload16(kc + i_*1024, (K_) + i_*1024); \
    const char* qc = Qbase + (size_t)(kb)*32768; \
    gload16(qc, (Q_)); gload16(qc + 1024, (Q_) + 1024); }

  f32x4 acc[4][4];
#pragma unroll
  for (int i = 0; i < 4; i++)
#pragma unroll
    for (int j = 0; j < 4; j++) { f32x4 z = {0.f,0.f,0.f,0.f}; acc[i][j] = z; }

  STAGE(0, Kd0, Qd0);
#pragma unroll
  for (int kb = 0; kb < 16; kb++) {
    // stage next chunk into the other buffer (loads stay in flight across barriers)
    if (kb < 15) {
      if (kb & 1) { STAGE(kb+1, Kd0, Qd0); } else { STAGE(kb+1, Kd1, Qd1); }
      asm volatile("s_waitcnt vmcnt(10)" ::: "memory");   // prev chunk complete
    } else {
      asm volatile("s_waitcnt vmcnt(0)" ::: "memory");
    }
    __builtin_amdgcn_s_barrier();
    __builtin_amdgcn_sched_barrier(0);
    const bf16* Kc = (kb & 1) ? Kb1 : Kb0;
    const bf16* Qc = (kb & 1) ? Qb1 : Qb0;
#pragma unroll
    for (int ks = 0; ks < 2; ks++) {
      int colx = (ks*32 + lg*8) ^ ((lr & 7) << 3);
      bf16x8 a[4];
#pragma unroll
      for (int mi = 0; mi < 4; mi++)
        a[mi] = *reinterpret_cast<const bf16x8*>(Qc + (mi*16 + lr)*64 + colx);
#pragma unroll
      for (int ni = 0; ni < 4; ni++) {
        bf16x8 bv2 = *reinterpret_cast<const bf16x8*>(Kc + (wave*64 + ni*16 + lr)*64 + colx);
#pragma unroll
        for (int mi = 0; mi < 4; mi++)
          acc[mi][ni] = __builtin_amdgcn_mfma_f32_16x16x32_bf16(a[mi], bv2, acc[mi][ni], 0, 0, 0);
      }
    }
    __builtin_amdgcn_s_barrier();        // all reads of this buffer done
    __builtin_amdgcn_sched_barrier(0);
  }
#undef STAGE
  // softmax over d (wave holds 64 d; combine 4 waves via red[4][64])
  const float scale = 0.03125f;
  float sums[4][4];
#pragma unroll
  for (int mi = 0; mi < 4; mi++)
#pragma unroll
    for (int r = 0; r < 4; r++) {
      float mx = fmaxf(fmaxf(acc[mi][0][r], acc[mi][1][r]), fmaxf(acc[mi][2][r], acc[mi][3][r]));
#pragma unroll
      for (int off = 1; off < 16; off <<= 1) mx = fmaxf(mx, __shfl_xor(mx, off, 64));
      red[wave][mi*16 + lg*4 + r] = mx;
    }
  __syncthreads();
#pragma unroll
  for (int mi = 0; mi < 4; mi++)
#pragma unroll
    for (int r = 0; r < 4; r++) {
      int clr = mi*16 + lg*4 + r;
      float mx = fmaxf(fmaxf(red[0][clr], red[1][clr]), fmaxf(red[2][clr], red[3][clr]));
      float s = 0.f;
#pragma unroll
      for (int ni = 0; ni < 4; ni++) {
        float p = __expf(scale*(acc[mi][ni][r] - mx));
        acc[mi][ni][r] = p; s += p;
      }
#pragma unroll
      for (int off = 1; off < 16; off <<= 1) s += __shfl_xor(s, off, 64);
      sums[mi][r] = s;
    }
  __syncthreads();
#pragma unroll
  for (int mi = 0; mi < 4; mi++)
#pragma unroll
    for (int r = 0; r < 4; r++) red[wave][mi*16 + lg*4 + r] = sums[mi][r];
  __syncthreads();
  // normalize + stage P strip into LDS (alias over K buffers) in swizzled layout
#pragma unroll
  for (int mi = 0; mi < 4; mi++)
#pragma unroll
    for (int r = 0; r < 4; r++) {
      int clr = mi*16 + lg*4 + r;
      float iv = 1.f/(red[0][clr] + red[1][clr] + red[2][clr] + red[3][clr]);
#pragma unroll
      for (int ni = 0; ni < 4; ni++) {
        int dl = ni*16 + lr;                     // d within wave's 64-chunk
        Pst[wave*4096 + clr*64 + (dl ^ ((clr & 7) << 3))] = (bf16)(acc[mi][ni][r]*iv);
      }
    }
  __syncthreads();
  // coalesced copy-out: 32 KB total; Pattn chunk kb gets rows cs*64..+64
  const uint4* ls = reinterpret_cast<const uint4*>(Pst);
#pragma unroll
  for (int i = 0; i < 8; i++) {
    int f = i*256 + t;              // 2048 uint4
    int kb = f >> 9, rem = f & 511;
    char* dst = (char*)Pattn + ((size_t)(bh*4 + kb)*256 + cs*64)*128 + (size_t)rem*16;
    *reinterpret_cast<uint4*>(dst) = ls[f];
  }
}

// ---------------- Kernel C: O = Pattn * V (K=256), fused deconv + bias + residual
__global__ __launch_bounds__(256, 4) void pv_deconv(const bf16* __restrict__ Pattn,
    const bf16* __restrict__ Vt, const float* __restrict__ qin,
    const float* __restrict__ wo, const float* __restrict__ bo,
    const float* __restrict__ gamma, float* __restrict__ outp) {
  int raw = blockIdx.x;
  int idx = raw >> 3;
  int pair = (raw & 7)*32 + (idx >> 2);   // (mb,bh); 4 tb-blocks share V chunk + XCD
  int tb = idx & 3;
  int mb = pair & 3, bh = pair >> 2;
  int h = bh & 7, b = bh >> 3;
  int t = threadIdx.x, wave = t >> 6, lane = t & 63, lg = lane >> 4, lr = lane & 15;
  __shared__ __attribute__((aligned(16))) char smem[40960];
  bf16* Pl   = reinterpret_cast<bf16*>(smem);            // 8192 B
  bf16* Vl   = reinterpret_cast<bf16*>(smem + 8192);     // 32768 B
  bf16* OlT  = reinterpret_cast<bf16*>(smem);            // 256*66*2 = 33792 B (post-loop)
  float* wo_s = reinterpret_cast<float*>(smem + 36864);  // 1024 B (post-loop)
  float* bo_s = reinterpret_cast<float*>(smem + 37888);  // 32 B
  const char* Pbase = (const char*)Pattn + ((size_t)bh*4*256 + tb*64)*128;
  const char* Vbase = (const char*)Vt + ((size_t)bh*4*1024 + mb*256)*128;
  f32x4 acc[4][4];
#pragma unroll
  for (int i = 0; i < 4; i++)
#pragma unroll
    for (int j = 0; j < 4; j++) { f32x4 z = {0.f,0.f,0.f,0.f}; acc[i][j] = z; }
  for (int kb = 0; kb < 4; kb++) {
    __syncthreads();
    {
      const char* pc = Pbase + (size_t)kb*32768 + wave*2048 + lane*16;
      char* pl = (char*)Pl + wave*2048;
#pragma unroll
      for (int i = 0; i < 2; i++) gload16(pc + i*1024, pl + i*1024);
      const char* vc = Vbase + (size_t)kb*131072 + wave*8192 + lane*16;
      char* vl = (char*)Vl + wave*8192;
#pragma unroll
      for (int i = 0; i < 8; i++) gload16(vc + i*1024, vl + i*1024);
    }
    __syncthreads();
#pragma unroll
    for (int ks = 0; ks < 2; ks++) {
      int colx = (ks*32 + lg*8) ^ ((lr & 7) << 3);
      bf16x8 a[4];
#pragma unroll
      for (int mi = 0; mi < 4; mi++)
        a[mi] = *reinterpret_cast<const bf16x8*>(Pl + (mi*16 + lr)*64 + colx);
#pragma unroll
      for (int ni = 0; ni < 4; ni++) {
        bf16x8 bv2 = *reinterpret_cast<const bf16x8*>(Vl + (wave*64 + ni*16 + lr)*64 + colx);
#pragma unroll
        for (int mi = 0; mi < 4; mi++)
          acc[mi][ni] = __builtin_amdgcn_mfma_f32_16x16x32_bf16(a[mi], bv2, acc[mi][ni], 0, 0, 0);
      }
    }
  }
  __syncthreads();   // all MFMA LDS reads done before OlT/wo_s overwrite
#pragma unroll
  for (int mi = 0; mi < 4; mi++)
#pragma unroll
    for (int ni = 0; ni < 4; ni++) {
      int l = wave*64 + ni*16 + lr;
      int cb = mi*16 + lg*4;
      bf16x4 p;
      p[0] = (bf16)acc[mi][ni][0]; p[1] = (bf16)acc[mi][ni][1];
      p[2] = (bf16)acc[mi][ni][2]; p[3] = (bf16)acc[mi][ni][3];
      *reinterpret_cast<bf16x4*>(OlT + l*66 + cb) = p;
    }
  wo_s[t] = wo[((size_t)(h*32 + tb*8 + (t>>5)))*32 + (t & 31)];
  if (t < 8) bo_s[t] = bo[h*32 + tb*8 + t];
  __syncthreads();
  // epilogue: deconv 2x2 stride 2 + bias + residual; fully coalesced float4 I/O
  int xq = t & 15, b5 = (t >> 4) & 1, ct = t >> 5;
  float2 wp[8];
#pragma unroll
  for (int j = 0; j < 8; j++)
    wp[j] = *reinterpret_cast<const float2*>(wo_s + ct*32 + j*4 + (1 - b5)*2);
  float bias = bo_s[ct];
  float gm = gamma[0];
  int co = h*32 + tb*8 + ct;
#pragma unroll
  for (int it = 0; it < 8; it++) {
    int y = it*2 + b5;
    int ll0 = it*32 + xq*2;
    bf16x4 o00 = *reinterpret_cast<const bf16x4*>(OlT + ll0*66 + ct*8);
    bf16x4 o01 = *reinterpret_cast<const bf16x4*>(OlT + ll0*66 + ct*8 + 4);
    bf16x4 o10 = *reinterpret_cast<const bf16x4*>(OlT + (ll0+1)*66 + ct*8);
    bf16x4 o11 = *reinterpret_cast<const bf16x4*>(OlT + (ll0+1)*66 + ct*8 + 4);
    float v0 = bias, v1 = bias, v2 = bias, v3 = bias;
#pragma unroll
    for (int j = 0; j < 4; j++) {
      float f0 = (float)o00[j], f1 = (float)o01[j];
      v0 += f0*wp[j].y;   v1 += f0*wp[j].x;
      v0 += f1*wp[4+j].y; v1 += f1*wp[4+j].x;
      float g0 = (float)o10[j], g1 = (float)o11[j];
      v2 += g0*wp[j].y;   v3 += g0*wp[j].x;
      v2 += g1*wp[4+j].y; v3 += g1*wp[4+j].x;
    }
    size_t oi = (((size_t)b*256 + co)*64 + (mb*16 + y))*64 + xq*4;
    float4 qv = *reinterpret_cast<const float4*>(qin + oi);
    float4 ov;
    ov.x = qv.x + gm*v0; ov.y = qv.y + gm*v1;
    ov.z = qv.z + gm*v2; ov.w = qv.w + gm*v3;
    *reinterpret_cast<float4*>(outp + oi) = ov;
  }
}

extern "C" void kernel_launch(void* const* d_in, const int* in_sizes, int n_in,
                              void* d_out, int out_size, void* d_ws, size_t ws_size,
                              hipStream_t stream) {
  const float* q  = (const float*)d_in[0];
  const float* k  = (const float*)d_in[1];
  const float* v  = (const float*)d_in[2];
  const float* wq = (const float*)d_in[3];
  const float* bq = (const float*)d_in[4];
  const float* wk = (const float*)d_in[5];
  const float* bk = (const float*)d_in[6];
  const float* wv = (const float*)d_in[7];
  const float* bv = (const float*)d_in[8];
  const float* wo = (const float*)d_in[9];
  const float* bo = (const float*)d_in[10];
  const float* gamma = (const float*)d_in[11];
  float* out = (float*)d_out;

  char* ws = (char*)d_ws;
  bf16* Pk    = (bf16*)(ws);              //  33,554,432 B
  bf16* Vt    = (bf16*)(ws + 33554432);   //  33,554,432 B
  bf16* Pattn = (bf16*)(ws + 67108864);   //   8,388,608 B
  bf16* Pq    = (bf16*)(ws + 75497472);   //  33,554,432 B

  proj_kqv<<<dim3(512, 8), 256, 0, stream>>>(k, q, v, wk, bk, wq, bq, wv, bv, Pk, Pq, Vt);
  attn_qk <<<dim3(256), 256, 0, stream>>>(Pq, Pk, Pattn);
  pv_deconv<<<dim3(1024), 256, 0, stream>>>(Pattn, Vt, q, wo, bo, gamma, out);
}

// Round 14
// 74.384 us; speedup vs baseline: 1.2012x; 1.0825x over previous
//
#include <hip/hip_runtime.h>
#include <hip/hip_bf16.h>

typedef __bf16 bf16;
typedef __bf16 bf16x4 __attribute__((ext_vector_type(4)));
typedef __bf16 bf16x8 __attribute__((ext_vector_type(8)));
typedef float f32x4 __attribute__((ext_vector_type(4)));
typedef long i64;

// async global->LDS, 16B per lane. LDS dest must be wave-uniform (HW adds lane*16).
__device__ __forceinline__ void gload16(const void* g, void* l) {
  __builtin_amdgcn_global_load_lds(
      (const __attribute__((address_space(1))) unsigned int*)g,
      (__attribute__((address_space(3))) unsigned int*)l, 16, 0, 0);
}

// Layouts:
//  Pq/Pk (fp8 e4m3): [bh][kb16][row c(256)][64 B]; 8-B granules, col-granule ^= (row&7)
//  Vt (bf16):    [bh][kb4][row l(1024)][64]  col-granule(16B) XOR (l&7)
//  Pattn (bf16): [bh][kb4][row c(256)][64]   col-granule(16B) XOR (c&7)

// ---------------- Kernel A: projections. x<128: k-pair, x<256: q-pair, else v.
__global__ __launch_bounds__(256) void proj_kqv(
    const float* __restrict__ kin, const float* __restrict__ qin,
    const float* __restrict__ vin,
    const float* __restrict__ wk, const float* __restrict__ bk,
    const float* __restrict__ wq, const float* __restrict__ bq,
    const float* __restrict__ wv, const float* __restrict__ bv,
    char* __restrict__ Pk, char* __restrict__ Pq, bf16* __restrict__ Vt) {
  int b = blockIdx.y;
  int x = blockIdx.x;
  int t = threadIdx.x;
  int wave = t >> 6, lane = t & 63;
  __shared__ __attribute__((aligned(16))) char smem[32768];
  if (x < 256) {
    bool isq = x >= 128;
    int g0 = (x & 127)*2;
    const float* in   = isq ? qin : kin;
    const float* w    = isq ? wq : wk;
    const float* bias = isq ? bq : bk;
    char* out         = isq ? Pq : Pk;
    int j = (t >> 3) & 7, n = t & 7;
    // weights FIRST (program order matters for FIFO vmcnt accounting)
    float4 wv0 = reinterpret_cast<const float4*>(w)[g0*8 + j];
    float  bb0 = bias[g0*8 + j];
    float4 wv1 = reinterpret_cast<const float4*>(w)[g0*8 + 8 + j];
    float  bb1 = bias[g0*8 + 8 + j];
    __builtin_amdgcn_sched_barrier(0);
    const char* s0 = (const char*)(in + ((size_t)b*256 + g0)*4096) + wave*4096 + lane*16;
    char* d0 = smem + wave*4096;
    char* d1 = smem + 16384 + wave*4096;
#pragma unroll
    for (int i = 0; i < 4; i++) gload16(s0 + i*1024, d0 + i*1024);
    __builtin_amdgcn_sched_barrier(0);
#pragma unroll
    for (int i = 0; i < 4; i++) gload16(s0 + 16384 + i*1024, d1 + i*1024);
    __builtin_amdgcn_sched_barrier(0);
    int h = g0 >> 5;                 // g0 even -> g0+1 shares h
    int bh = b*8 + h;

#define CONVST(bufp, g, wvv, bj) { \
    const float* chf = reinterpret_cast<const float*>(bufp); \
    int c0l = ((g) & 31)*8; \
    _Pragma("unroll") \
    for (int p = 0; p < 4; p++) { \
      int kb = p*4 + wave; \
      int m = kb*2 + (n >> 2); \
      int n0 = (n & 3)*8; \
      float rr0[16], rr1[16]; \
      const float4* R0 = reinterpret_cast<const float4*>(chf + (2*m)*64 + 2*n0); \
      const float4* R1 = reinterpret_cast<const float4*>(chf + (2*m+1)*64 + 2*n0); \
      _Pragma("unroll") \
      for (int u = 0; u < 4; u++) { \
        *reinterpret_cast<float4*>(rr0 + u*4) = R0[u]; \
        *reinterpret_cast<float4*>(rr1 + u*4) = R1[u]; \
      } \
      float ov[8]; \
      _Pragma("unroll") \
      for (int u = 0; u < 8; u++) \
        ov[u] = (bj) + (wvv).x*rr0[2*u] + (wvv).y*rr0[2*u+1] + (wvv).z*rr1[2*u] + (wvv).w*rr1[2*u+1]; \
      int w0 = 0, w1 = 0; \
      w0 = __builtin_amdgcn_cvt_pk_fp8_f32(ov[0], ov[1], w0, false); \
      w0 = __builtin_amdgcn_cvt_pk_fp8_f32(ov[2], ov[3], w0, true); \
      w1 = __builtin_amdgcn_cvt_pk_fp8_f32(ov[4], ov[5], w1, false); \
      w1 = __builtin_amdgcn_cvt_pk_fp8_f32(ov[6], ov[7], w1, true); \
      size_t off = (((size_t)bh*16 + kb)*256 + c0l + j)*64 + (size_t)((n ^ j)*8); \
      int2 st; st.x = w0; st.y = w1; \
      *reinterpret_cast<int2*>(out + off) = st; \
    } }

    asm volatile("s_waitcnt vmcnt(4)" ::: "memory");   // weights + ch0 loads done
    __builtin_amdgcn_s_barrier();
    CONVST(smem, g0, wv0, bb0);                         // 4 stores issued
    __builtin_amdgcn_sched_barrier(0);
    asm volatile("s_waitcnt vmcnt(4)" ::: "memory");   // ch1 loads done; stores in flight
    __builtin_amdgcn_s_barrier();
    CONVST(smem + 16384, g0 + 1, wv1, bb1);
#undef CONVST
  } else {
    // ---- v projection into swizzled chunk-transposed Vt (pad 67: 2-way max)
    float* ch = reinterpret_cast<float*>(smem);
    int r = x - 256;
    int m = r & 31, h = r >> 5;
    {
      int seg = t >> 2, part = t & 3;
      int gl = seg >> 1, ky = seg & 1;
      const float* src = vin + (((size_t)b*256 + h*32 + gl)*64 + (2*m + ky))*64;
      float* drow = ch + (gl*2 + ky)*67;
#pragma unroll
      for (int i = 0; i < 4; i++) {
        float4 v = reinterpret_cast<const float4*>(src)[part + i*4];
        int x0 = (part + i*4)*4;
        drow[x0]=v.x; drow[x0+1]=v.y; drow[x0+2]=v.z; drow[x0+3]=v.w;
      }
    }
    int cgrp = t & 31, lgr = t >> 5;
    int c0 = cgrp*8;
    float4 wv8[8]; float bb8[8];
#pragma unroll
    for (int u = 0; u < 8; u++) {
      wv8[u] = reinterpret_cast<const float4*>(wv)[h*256 + c0 + u];
      bb8[u] = bv[h*256 + c0 + u];
    }
    __syncthreads();
    const float* r0 = ch + (cgrp*2 + 0)*67;
    const float* r1 = ch + (cgrp*2 + 1)*67;
    int bh = b*8 + h;
    bf16* base = Vt + ((size_t)bh*4 + (c0 >> 6))*1024*64;
    int colx = (c0 & 63) ^ (lgr << 3);
#pragma unroll
    for (int p = 0; p < 4; p++) {
      int n = p*8 + lgr;
      int l = m*32 + n;
      float c00 = r0[2*n], c01 = r0[2*n+1], c10 = r1[2*n], c11 = r1[2*n+1];
      bf16x8 o;
#pragma unroll
      for (int u = 0; u < 8; u++)
        o[u] = (bf16)(bb8[u] + wv8[u].x*c00 + wv8[u].y*c01 + wv8[u].z*c10 + wv8[u].w*c11);
      *reinterpret_cast<bf16x8*>(base + (size_t)l*64 + colx) = o;
    }
  }
}

// ---------------- Kernel B: S = Q K^T (fp8 MFMA) + softmax -> Pattn.  BM=64,
// 256 blocks, 4 waves; wave tile 64c x 64d.  2-phase counted-vmcnt pipeline:
// K+Q fp8 double-buffered LDS via gload16, vmcnt(5) never 0 in steady state.
__global__ __launch_bounds__(256, 2) void attn_qk(
    const char* __restrict__ Pq, const char* __restrict__ Pk,
    bf16* __restrict__ Pattn) {
  int raw = blockIdx.x;
  int idx = raw >> 3;
  int bh = (raw & 7)*8 + (idx >> 2);   // 4 c-strips of one bh share an XCD
  int cs = idx & 3;
  int t = threadIdx.x, wave = t >> 6, lane = t & 63, lg = lane >> 4, lr = lane & 15;
  __shared__ __attribute__((aligned(16))) char smem[40960];
  char* Kb0 = smem;                    // 16 KB
  char* Kb1 = smem + 16384;            // 16 KB
  char* Qb0 = smem + 32768;            //  4 KB
  char* Qb1 = smem + 36864;            //  4 KB
  float (*red)[64] = reinterpret_cast<float (*)[64]>(smem + 32768);  // post-loop alias
  bf16* Pst = reinterpret_cast<bf16*>(smem);            // 32 KB post-loop alias
  const char* Kbase = Pk + (size_t)bh*262144 + wave*4096 + lane*16;
  const char* Qbase = Pq + (size_t)bh*262144 + (size_t)cs*4096 + wave*1024 + lane*16;
  char* Kd0 = Kb0 + wave*4096;  char* Kd1 = Kb1 + wave*4096;
  char* Qd0 = Qb0 + wave*1024;  char* Qd1 = Qb1 + wave*1024;

#define STAGE(kb, K_, Q_) { \
    const char* kc = Kbase + (size_t)(kb)*16384; \
    _Pragma("unroll") \
    for (int i_ = 0; i_ < 4; i_++) gload16(kc + i_*1024, (K_) + i_*1024); \
    gload16(Qbase + (size_t)(kb)*16384, (Q_)); }

  f32x4 acc[4][4];
#pragma unroll
  for (int i = 0; i < 4; i++)
#pragma unroll
    for (int j = 0; j < 4; j++) { f32x4 z = {0.f,0.f,0.f,0.f}; acc[i][j] = z; }

  STAGE(0, Kd0, Qd0);
#pragma unroll
  for (int kb = 0; kb < 16; kb++) {
    // stage next chunk into the other buffer (loads stay in flight across barriers)
    if (kb < 15) {
      if (kb & 1) { STAGE(kb+1, Kd0, Qd0); } else { STAGE(kb+1, Kd1, Qd1); }
      asm volatile("s_waitcnt vmcnt(5)" ::: "memory");   // prev chunk complete
    } else {
      asm volatile("s_waitcnt vmcnt(0)" ::: "memory");
    }
    __builtin_amdgcn_s_barrier();
    __builtin_amdgcn_sched_barrier(0);
    const char* Kc = (kb & 1) ? Kb1 : Kb0;
    const char* Qc = (kb & 1) ? Qb1 : Qb0;
#pragma unroll
    for (int ks = 0; ks < 2; ks++) {
      int colx = (ks*32 + lg*8) ^ ((lr & 7) << 3);
      i64 a[4];
#pragma unroll
      for (int mi = 0; mi < 4; mi++)
        a[mi] = *reinterpret_cast<const i64*>(Qc + (mi*16 + lr)*64 + colx);
#pragma unroll
      for (int ni = 0; ni < 4; ni++) {
        i64 bfr = *reinterpret_cast<const i64*>(Kc + (wave*64 + ni*16 + lr)*64 + colx);
#pragma unroll
        for (int mi = 0; mi < 4; mi++)
          acc[mi][ni] = __builtin_amdgcn_mfma_f32_16x16x32_fp8_fp8(a[mi], bfr, acc[mi][ni], 0, 0, 0);
      }
    }
    __builtin_amdgcn_s_barrier();        // all reads of this buffer done
    __builtin_amdgcn_sched_barrier(0);
  }
#undef STAGE
  // softmax over d (wave holds 64 d; combine 4 waves via red[4][64])
  const float scale = 0.03125f;
  float sums[4][4];
#pragma unroll
  for (int mi = 0; mi < 4; mi++)
#pragma unroll
    for (int r = 0; r < 4; r++) {
      float mx = fmaxf(fmaxf(acc[mi][0][r], acc[mi][1][r]), fmaxf(acc[mi][2][r], acc[mi][3][r]));
#pragma unroll
      for (int off = 1; off < 16; off <<= 1) mx = fmaxf(mx, __shfl_xor(mx, off, 64));
      red[wave][mi*16 + lg*4 + r] = mx;
    }
  __syncthreads();
#pragma unroll
  for (int mi = 0; mi < 4; mi++)
#pragma unroll
    for (int r = 0; r < 4; r++) {
      int clr = mi*16 + lg*4 + r;
      float mx = fmaxf(fmaxf(red[0][clr], red[1][clr]), fmaxf(red[2][clr], red[3][clr]));
      float s = 0.f;
#pragma unroll
      for (int ni = 0; ni < 4; ni++) {
        float p = __expf(scale*(acc[mi][ni][r] - mx));
        acc[mi][ni][r] = p; s += p;
      }
#pragma unroll
      for (int off = 1; off < 16; off <<= 1) s += __shfl_xor(s, off, 64);
      sums[mi][r] = s;
    }
  __syncthreads();
#pragma unroll
  for (int mi = 0; mi < 4; mi++)
#pragma unroll
    for (int r = 0; r < 4; r++) red[wave][mi*16 + lg*4 + r] = sums[mi][r];
  __syncthreads();
  // normalize + stage P strip into LDS (alias over K buffers) in swizzled layout
#pragma unroll
  for (int mi = 0; mi < 4; mi++)
#pragma unroll
    for (int r = 0; r < 4; r++) {
      int clr = mi*16 + lg*4 + r;
      float iv = 1.f/(red[0][clr] + red[1][clr] + red[2][clr] + red[3][clr]);
#pragma unroll
      for (int ni = 0; ni < 4; ni++) {
        int dl = ni*16 + lr;                     // d within wave's 64-chunk
        Pst[wave*4096 + clr*64 + (dl ^ ((clr & 7) << 3))] = (bf16)(acc[mi][ni][r]*iv);
      }
    }
  __syncthreads();
  // coalesced copy-out: 32 KB total; Pattn chunk kb gets rows cs*64..+64
  const uint4* ls = reinterpret_cast<const uint4*>(Pst);
#pragma unroll
  for (int i = 0; i < 8; i++) {
    int f = i*256 + t;              // 2048 uint4
    int kb = f >> 9, rem = f & 511;
    char* dst = (char*)Pattn + ((size_t)(bh*4 + kb)*256 + cs*64)*128 + (size_t)rem*16;
    *reinterpret_cast<uint4*>(dst) = ls[f];
  }
}

// ---------------- Kernel C: O = Pattn * V (K=256), fused deconv + bias + residual
__global__ __launch_bounds__(256, 4) void pv_deconv(const bf16* __restrict__ Pattn,
    const bf16* __restrict__ Vt, const float* __restrict__ qin,
    const float* __restrict__ wo, const float* __restrict__ bo,
    const float* __restrict__ gamma, float* __restrict__ outp) {
  int raw = blockIdx.x;
  int idx = raw >> 3;
  int pair = (raw & 7)*32 + (idx >> 2);   // (mb,bh); 4 tb-blocks share V chunk + XCD
  int tb = idx & 3;
  int mb = pair & 3, bh = pair >> 2;
  int h = bh & 7, b = bh >> 3;
  int t = threadIdx.x, wave = t >> 6, lane = t & 63, lg = lane >> 4, lr = lane & 15;
  __shared__ __attribute__((aligned(16))) char smem[40960];
  bf16* Pl   = reinterpret_cast<bf16*>(smem);            // 8192 B
  bf16* Vl   = reinterpret_cast<bf16*>(smem + 8192);     // 32768 B
  bf16* OlT  = reinterpret_cast<bf16*>(smem);            // 256*66*2 = 33792 B (post-loop)
  float* wo_s = reinterpret_cast<float*>(smem + 36864);  // 1024 B (post-loop)
  float* bo_s = reinterpret_cast<float*>(smem + 37888);  // 32 B
  const char* Pbase = (const char*)Pattn + ((size_t)bh*4*256 + tb*64)*128;
  const char* Vbase = (const char*)Vt + ((size_t)bh*4*1024 + mb*256)*128;
  f32x4 acc[4][4];
#pragma unroll
  for (int i = 0; i < 4; i++)
#pragma unroll
    for (int j = 0; j < 4; j++) { f32x4 z = {0.f,0.f,0.f,0.f}; acc[i][j] = z; }
  for (int kb = 0; kb < 4; kb++) {
    __syncthreads();
    {
      const char* pc = Pbase + (size_t)kb*32768 + wave*2048 + lane*16;
      char* pl = (char*)Pl + wave*2048;
#pragma unroll
      for (int i = 0; i < 2; i++) gload16(pc + i*1024, pl + i*1024);
      const char* vc = Vbase + (size_t)kb*131072 + wave*8192 + lane*16;
      char* vl = (char*)Vl + wave*8192;
#pragma unroll
      for (int i = 0; i < 8; i++) gload16(vc + i*1024, vl + i*1024);
    }
    __syncthreads();
#pragma unroll
    for (int ks = 0; ks < 2; ks++) {
      int colx = (ks*32 + lg*8) ^ ((lr & 7) << 3);
      bf16x8 a[4];
#pragma unroll
      for (int mi = 0; mi < 4; mi++)
        a[mi] = *reinterpret_cast<const bf16x8*>(Pl + (mi*16 + lr)*64 + colx);
#pragma unroll
      for (int ni = 0; ni < 4; ni++) {
        bf16x8 bv2 = *reinterpret_cast<const bf16x8*>(Vl + (wave*64 + ni*16 + lr)*64 + colx);
#pragma unroll
        for (int mi = 0; mi < 4; mi++)
          acc[mi][ni] = __builtin_amdgcn_mfma_f32_16x16x32_bf16(a[mi], bv2, acc[mi][ni], 0, 0, 0);
      }
    }
  }
  __syncthreads();   // all MFMA LDS reads done before OlT/wo_s overwrite
#pragma unroll
  for (int mi = 0; mi < 4; mi++)
#pragma unroll
    for (int ni = 0; ni < 4; ni++) {
      int l = wave*64 + ni*16 + lr;
      int cb = mi*16 + lg*4;
      bf16x4 p;
      p[0] = (bf16)acc[mi][ni][0]; p[1] = (bf16)acc[mi][ni][1];
      p[2] = (bf16)acc[mi][ni][2]; p[3] = (bf16)acc[mi][ni][3];
      *reinterpret_cast<bf16x4*>(OlT + l*66 + cb) = p;
    }
  wo_s[t] = wo[((size_t)(h*32 + tb*8 + (t>>5)))*32 + (t & 31)];
  if (t < 8) bo_s[t] = bo[h*32 + tb*8 + t];
  __syncthreads();
  // epilogue: deconv 2x2 stride 2 + bias + residual; fully coalesced float4 I/O
  int xq = t & 15, b5 = (t >> 4) & 1, ct = t >> 5;
  float2 wp[8];
#pragma unroll
  for (int j = 0; j < 8; j++)
    wp[j] = *reinterpret_cast<const float2*>(wo_s + ct*32 + j*4 + (1 - b5)*2);
  float bias = bo_s[ct];
  float gm = gamma[0];
  int co = h*32 + tb*8 + ct;
#pragma unroll
  for (int it = 0; it < 8; it++) {
    int y = it*2 + b5;
    int ll0 = it*32 + xq*2;
    bf16x4 o00 = *reinterpret_cast<const bf16x4*>(OlT + ll0*66 + ct*8);
    bf16x4 o01 = *reinterpret_cast<const bf16x4*>(OlT + ll0*66 + ct*8 + 4);
    bf16x4 o10 = *reinterpret_cast<const bf16x4*>(OlT + (ll0+1)*66 + ct*8);
    bf16x4 o11 = *reinterpret_cast<const bf16x4*>(OlT + (ll0+1)*66 + ct*8 + 4);
    float v0 = bias, v1 = bias, v2 = bias, v3 = bias;
#pragma unroll
    for (int j = 0; j < 4; j++) {
      float f0 = (float)o00[j], f1 = (float)o01[j];
      v0 += f0*wp[j].y;   v1 += f0*wp[j].x;
      v0 += f1*wp[4+j].y; v1 += f1*wp[4+j].x;
      float g0 = (float)o10[j], g1 = (float)o11[j];
      v2 += g0*wp[j].y;   v3 += g0*wp[j].x;
      v2 += g1*wp[4+j].y; v3 += g1*wp[4+j].x;
    }
    size_t oi = (((size_t)b*256 + co)*64 + (mb*16 + y))*64 + xq*4;
    float4 qv = *reinterpret_cast<const float4*>(qin + oi);
    float4 ov;
    ov.x = qv.x + gm*v0; ov.y = qv.y + gm*v1;
    ov.z = qv.z + gm*v2; ov.w = qv.w + gm*v3;
    *reinterpret_cast<float4*>(outp + oi) = ov;
  }
}

extern "C" void kernel_launch(void* const* d_in, const int* in_sizes, int n_in,
                              void* d_out, int out_size, void* d_ws, size_t ws_size,
                              hipStream_t stream) {
  const float* q  = (const float*)d_in[0];
  const float* k  = (const float*)d_in[1];
  const float* v  = (const float*)d_in[2];
  const float* wq = (const float*)d_in[3];
  const float* bq = (const float*)d_in[4];
  const float* wk = (const float*)d_in[5];
  const float* bk = (const float*)d_in[6];
  const float* wv = (const float*)d_in[7];
  const float* bv = (const float*)d_in[8];
  const float* wo = (const float*)d_in[9];
  const float* bo = (const float*)d_in[10];
  const float* gamma = (const float*)d_in[11];
  float* out = (float*)d_out;

  char* ws = (char*)d_ws;
  char* Pk    = ws;                       //  16,777,216 B (fp8)
  char* Pq    = ws + 16777216;            //  16,777,216 B (fp8)
  bf16* Vt    = (bf16*)(ws + 33554432);   //  33,554,432 B
  bf16* Pattn = (bf16*)(ws + 67108864);   //   8,388,608 B

  proj_kqv<<<dim3(512, 8), 256, 0, stream>>>(k, q, v, wk, bk, wq, bq, wv, bv, Pk, Pq, Vt);
  attn_qk <<<dim3(256), 256, 0, stream>>>(Pq, Pk, Pattn);
  pv_deconv<<<dim3(1024), 256, 0, stream>>>(Pattn, Vt, q, wo, bo, gamma, out);
}

// Round 15
// 69.509 us; speedup vs baseline: 1.2855x; 1.0701x over previous
//
#include <hip/hip_runtime.h>
#include <hip/hip_bf16.h>

typedef __bf16 bf16;
typedef __bf16 bf16x4 __attribute__((ext_vector_type(4)));
typedef __bf16 bf16x8 __attribute__((ext_vector_type(8)));
typedef float f32x4 __attribute__((ext_vector_type(4)));
typedef long i64;

// async global->LDS, 16B per lane. LDS dest must be wave-uniform (HW adds lane*16).
__device__ __forceinline__ void gload16(const void* g, void* l) {
  __builtin_amdgcn_global_load_lds(
      (const __attribute__((address_space(1))) unsigned int*)g,
      (__attribute__((address_space(3))) unsigned int*)l, 16, 0, 0);
}

// All intermediates fp8 e4m3, 64-B rows, 8-B granules, granule-XOR (row&7):
//  Pq/Pk: [bh][kb16][row c(256)][64 B]   (k-dim l)   value = P
//  Vt:    [bh][db4] [row l(1024)][64 B]  (k-dim d)   value = 8*V
//  Pattn: [bh][db4] [row c(256)][64 B]   (k-dim d)   value = 32*P
// PV accumulator rescale: 1/(8*32) = 1/256.

// ---------------- Kernel A: projections. x<128: k-pair, x<256: q-pair, else v.
__global__ __launch_bounds__(256) void proj_kqv(
    const float* __restrict__ kin, const float* __restrict__ qin,
    const float* __restrict__ vin,
    const float* __restrict__ wk, const float* __restrict__ bk,
    const float* __restrict__ wq, const float* __restrict__ bq,
    const float* __restrict__ wv, const float* __restrict__ bv,
    char* __restrict__ Pk, char* __restrict__ Pq, char* __restrict__ Vt) {
  int b = blockIdx.y;
  int x = blockIdx.x;
  int t = threadIdx.x;
  int wave = t >> 6, lane = t & 63;
  __shared__ __attribute__((aligned(16))) char smem[32768];
  if (x < 256) {
    bool isq = x >= 128;
    int g0 = (x & 127)*2;
    const float* in   = isq ? qin : kin;
    const float* w    = isq ? wq : wk;
    const float* bias = isq ? bq : bk;
    char* out         = isq ? Pq : Pk;
    int j = (t >> 3) & 7, n = t & 7;
    // weights FIRST (program order matters for FIFO vmcnt accounting)
    float4 wv0 = reinterpret_cast<const float4*>(w)[g0*8 + j];
    float  bb0 = bias[g0*8 + j];
    float4 wv1 = reinterpret_cast<const float4*>(w)[g0*8 + 8 + j];
    float  bb1 = bias[g0*8 + 8 + j];
    __builtin_amdgcn_sched_barrier(0);
    const char* s0 = (const char*)(in + ((size_t)b*256 + g0)*4096) + wave*4096 + lane*16;
    char* d0 = smem + wave*4096;
    char* d1 = smem + 16384 + wave*4096;
#pragma unroll
    for (int i = 0; i < 4; i++) gload16(s0 + i*1024, d0 + i*1024);
    __builtin_amdgcn_sched_barrier(0);
#pragma unroll
    for (int i = 0; i < 4; i++) gload16(s0 + 16384 + i*1024, d1 + i*1024);
    __builtin_amdgcn_sched_barrier(0);
    int h = g0 >> 5;                 // g0 even -> g0+1 shares h
    int bh = b*8 + h;

#define CONVST(bufp, g, wvv, bj) { \
    const float* chf = reinterpret_cast<const float*>(bufp); \
    int c0l = ((g) & 31)*8; \
    _Pragma("unroll") \
    for (int p = 0; p < 4; p++) { \
      int kb = p*4 + wave; \
      int m = kb*2 + (n >> 2); \
      int n0 = (n & 3)*8; \
      float rr0[16], rr1[16]; \
      const float4* R0 = reinterpret_cast<const float4*>(chf + (2*m)*64 + 2*n0); \
      const float4* R1 = reinterpret_cast<const float4*>(chf + (2*m+1)*64 + 2*n0); \
      _Pragma("unroll") \
      for (int u = 0; u < 4; u++) { \
        *reinterpret_cast<float4*>(rr0 + u*4) = R0[u]; \
        *reinterpret_cast<float4*>(rr1 + u*4) = R1[u]; \
      } \
      float ov[8]; \
      _Pragma("unroll") \
      for (int u = 0; u < 8; u++) \
        ov[u] = (bj) + (wvv).x*rr0[2*u] + (wvv).y*rr0[2*u+1] + (wvv).z*rr1[2*u] + (wvv).w*rr1[2*u+1]; \
      int w0 = 0, w1 = 0; \
      w0 = __builtin_amdgcn_cvt_pk_fp8_f32(ov[0], ov[1], w0, false); \
      w0 = __builtin_amdgcn_cvt_pk_fp8_f32(ov[2], ov[3], w0, true); \
      w1 = __builtin_amdgcn_cvt_pk_fp8_f32(ov[4], ov[5], w1, false); \
      w1 = __builtin_amdgcn_cvt_pk_fp8_f32(ov[6], ov[7], w1, true); \
      size_t off = (((size_t)bh*16 + kb)*256 + c0l + j)*64 + (size_t)((n ^ j)*8); \
      int2 st; st.x = w0; st.y = w1; \
      *reinterpret_cast<int2*>(out + off) = st; \
    } }

    asm volatile("s_waitcnt vmcnt(4)" ::: "memory");   // weights + ch0 loads done
    __builtin_amdgcn_s_barrier();
    CONVST(smem, g0, wv0, bb0);                         // 4 stores issued
    __builtin_amdgcn_sched_barrier(0);
    asm volatile("s_waitcnt vmcnt(4)" ::: "memory");   // ch1 loads done; stores in flight
    __builtin_amdgcn_s_barrier();
    CONVST(smem + 16384, g0 + 1, wv1, bb1);
#undef CONVST
  } else {
    // ---- v projection into swizzled chunk-transposed Vt (fp8, x8 scale)
    float* ch = reinterpret_cast<float*>(smem);
    int r = x - 256;
    int m = r & 31, h = r >> 5;
    {
      int seg = t >> 2, part = t & 3;
      int gl = seg >> 1, ky = seg & 1;
      const float* src = vin + (((size_t)b*256 + h*32 + gl)*64 + (2*m + ky))*64;
      float* drow = ch + (gl*2 + ky)*67;
#pragma unroll
      for (int i = 0; i < 4; i++) {
        float4 v = reinterpret_cast<const float4*>(src)[part + i*4];
        int x0 = (part + i*4)*4;
        drow[x0]=v.x; drow[x0+1]=v.y; drow[x0+2]=v.z; drow[x0+3]=v.w;
      }
    }
    int cgrp = t & 31, lgr = t >> 5;
    int c0 = cgrp*8;
    float4 wv8[8]; float bb8[8];
#pragma unroll
    for (int u = 0; u < 8; u++) {
      wv8[u] = reinterpret_cast<const float4*>(wv)[h*256 + c0 + u];
      bb8[u] = bv[h*256 + c0 + u];
    }
    __syncthreads();
    const float* r0 = ch + (cgrp*2 + 0)*67;
    const float* r1 = ch + (cgrp*2 + 1)*67;
    int bh = b*8 + h;
    char* base = Vt + ((size_t)bh*4 + (c0 >> 6))*65536;
    int gsw = ((cgrp & 7) ^ lgr)*8;
#pragma unroll
    for (int p = 0; p < 4; p++) {
      int n = p*8 + lgr;
      int l = m*32 + n;               // l&7 == lgr
      float c00 = r0[2*n], c01 = r0[2*n+1], c10 = r1[2*n], c11 = r1[2*n+1];
      float ov[8];
#pragma unroll
      for (int u = 0; u < 8; u++)
        ov[u] = 8.f*(bb8[u] + wv8[u].x*c00 + wv8[u].y*c01 + wv8[u].z*c10 + wv8[u].w*c11);
      int w0 = 0, w1 = 0;
      w0 = __builtin_amdgcn_cvt_pk_fp8_f32(ov[0], ov[1], w0, false);
      w0 = __builtin_amdgcn_cvt_pk_fp8_f32(ov[2], ov[3], w0, true);
      w1 = __builtin_amdgcn_cvt_pk_fp8_f32(ov[4], ov[5], w1, false);
      w1 = __builtin_amdgcn_cvt_pk_fp8_f32(ov[6], ov[7], w1, true);
      int2 st; st.x = w0; st.y = w1;
      *reinterpret_cast<int2*>(base + (size_t)l*64 + gsw) = st;
    }
  }
}

// ---------------- Kernel B: S = Q K^T (fp8 MFMA) + softmax -> Pattn (fp8 x32).
__global__ __launch_bounds__(256, 2) void attn_qk(
    const char* __restrict__ Pq, const char* __restrict__ Pk,
    char* __restrict__ Pattn) {
  int raw = blockIdx.x;
  int idx = raw >> 3;
  int bh = (raw & 7)*8 + (idx >> 2);   // 4 c-strips of one bh share an XCD
  int cs = idx & 3;
  int t = threadIdx.x, wave = t >> 6, lane = t & 63, lg = lane >> 4, lr = lane & 15;
  __shared__ __attribute__((aligned(16))) char smem[40960];
  char* Kb0 = smem;                    // 16 KB
  char* Kb1 = smem + 16384;            // 16 KB
  char* Qb0 = smem + 32768;            //  4 KB
  char* Qb1 = smem + 36864;            //  4 KB
  float (*red)[64] = reinterpret_cast<float (*)[64]>(smem + 32768);  // post-loop alias
  char* Pst = smem;                    // 16 KB post-loop alias
  const char* Kbase = Pk + (size_t)bh*262144 + wave*4096 + lane*16;
  const char* Qbase = Pq + (size_t)bh*262144 + (size_t)cs*4096 + wave*1024 + lane*16;
  char* Kd0 = Kb0 + wave*4096;  char* Kd1 = Kb1 + wave*4096;
  char* Qd0 = Qb0 + wave*1024;  char* Qd1 = Qb1 + wave*1024;

#define STAGE(kb, K_, Q_) { \
    const char* kc = Kbase + (size_t)(kb)*16384; \
    _Pragma("unroll") \
    for (int i_ = 0; i_ < 4; i_++) gload16(kc + i_*1024, (K_) + i_*1024); \
    gload16(Qbase + (size_t)(kb)*16384, (Q_)); }

  f32x4 acc[4][4];
#pragma unroll
  for (int i = 0; i < 4; i++)
#pragma unroll
    for (int j = 0; j < 4; j++) { f32x4 z = {0.f,0.f,0.f,0.f}; acc[i][j] = z; }

  STAGE(0, Kd0, Qd0);
#pragma unroll
  for (int kb = 0; kb < 16; kb++) {
    if (kb < 15) {
      if (kb & 1) { STAGE(kb+1, Kd0, Qd0); } else { STAGE(kb+1, Kd1, Qd1); }
      asm volatile("s_waitcnt vmcnt(5)" ::: "memory");   // prev chunk complete
    } else {
      asm volatile("s_waitcnt vmcnt(0)" ::: "memory");
    }
    __builtin_amdgcn_s_barrier();
    __builtin_amdgcn_sched_barrier(0);
    const char* Kc = (kb & 1) ? Kb1 : Kb0;
    const char* Qc = (kb & 1) ? Qb1 : Qb0;
#pragma unroll
    for (int ks = 0; ks < 2; ks++) {
      int colx = (ks*32 + lg*8) ^ ((lr & 7) << 3);
      i64 a[4];
#pragma unroll
      for (int mi = 0; mi < 4; mi++)
        a[mi] = *reinterpret_cast<const i64*>(Qc + (mi*16 + lr)*64 + colx);
#pragma unroll
      for (int ni = 0; ni < 4; ni++) {
        i64 bfr = *reinterpret_cast<const i64*>(Kc + (wave*64 + ni*16 + lr)*64 + colx);
#pragma unroll
        for (int mi = 0; mi < 4; mi++)
          acc[mi][ni] = __builtin_amdgcn_mfma_f32_16x16x32_fp8_fp8(a[mi], bfr, acc[mi][ni], 0, 0, 0);
      }
    }
    __builtin_amdgcn_s_barrier();        // all reads of this buffer done
    __builtin_amdgcn_sched_barrier(0);
  }
#undef STAGE
  // softmax over d (wave holds 64 d; combine 4 waves via red[4][64])
  const float scale = 0.03125f;
  float sums[4][4];
#pragma unroll
  for (int mi = 0; mi < 4; mi++)
#pragma unroll
    for (int r = 0; r < 4; r++) {
      float mx = fmaxf(fmaxf(acc[mi][0][r], acc[mi][1][r]), fmaxf(acc[mi][2][r], acc[mi][3][r]));
#pragma unroll
      for (int off = 1; off < 16; off <<= 1) mx = fmaxf(mx, __shfl_xor(mx, off, 64));
      red[wave][mi*16 + lg*4 + r] = mx;
    }
  __syncthreads();
#pragma unroll
  for (int mi = 0; mi < 4; mi++)
#pragma unroll
    for (int r = 0; r < 4; r++) {
      int clr = mi*16 + lg*4 + r;
      float mx = fmaxf(fmaxf(red[0][clr], red[1][clr]), fmaxf(red[2][clr], red[3][clr]));
      float s = 0.f;
#pragma unroll
      for (int ni = 0; ni < 4; ni++) {
        float p = __expf(scale*(acc[mi][ni][r] - mx));
        acc[mi][ni][r] = p; s += p;
      }
#pragma unroll
      for (int off = 1; off < 16; off <<= 1) s += __shfl_xor(s, off, 64);
      sums[mi][r] = s;
    }
  __syncthreads();
#pragma unroll
  for (int mi = 0; mi < 4; mi++)
#pragma unroll
    for (int r = 0; r < 4; r++) red[wave][mi*16 + lg*4 + r] = sums[mi][r];
  __syncthreads();
  // normalize (x32) + stage P strip into LDS as fp8, swizzled layout
#pragma unroll
  for (int mi = 0; mi < 4; mi++)
#pragma unroll
    for (int r = 0; r < 4; r++) {
      int clr = mi*16 + lg*4 + r;
      float iv = 32.f/(red[0][clr] + red[1][clr] + red[2][clr] + red[3][clr]);
      char* prow = Pst + wave*4096 + clr*64;
      int xr = (clr & 7) << 3;
#pragma unroll
      for (int ni = 0; ni < 4; ni += 2) {
        int pk2 = __builtin_amdgcn_cvt_pk_fp8_f32(acc[mi][ni][r]*iv, acc[mi][ni+1][r]*iv, 0, false);
        prow[(ni*16 + lr) ^ xr]     = (char)(pk2 & 0xff);
        prow[((ni+1)*16 + lr) ^ xr] = (char)((pk2 >> 8) & 0xff);
      }
    }
  __syncthreads();
  // coalesced copy-out: 16 KB total; Pattn chunk kb gets rows cs*64..+64
  const uint4* ls = reinterpret_cast<const uint4*>(Pst);
#pragma unroll
  for (int i = 0; i < 4; i++) {
    int f = i*256 + t;              // 1024 uint4
    int kb = f >> 8, rem = f & 255;
    char* dst = Pattn + ((size_t)(bh*4 + kb)*256 + cs*64)*64 + (size_t)rem*16;
    *reinterpret_cast<uint4*>(dst) = ls[f];
  }
}

// ---------------- Kernel C: O = Pattn * V (fp8 MFMA), fused deconv + residual
__global__ __launch_bounds__(256, 4) void pv_deconv(const char* __restrict__ Pattn,
    const char* __restrict__ Vt, const float* __restrict__ qin,
    const float* __restrict__ wo, const float* __restrict__ bo,
    const float* __restrict__ gamma, float* __restrict__ outp) {
  int raw = blockIdx.x;
  int idx = raw >> 3;
  int pair = (raw & 7)*32 + (idx >> 2);   // (mb,bh); 4 tb-blocks share V chunk + XCD
  int tb = idx & 3;
  int mb = pair & 3, bh = pair >> 2;
  int h = bh & 7, b = bh >> 3;
  int t = threadIdx.x, wave = t >> 6, lane = t & 63, lg = lane >> 4, lr = lane & 15;
  __shared__ __attribute__((aligned(16))) char smem[40960];
  char* Pl   = smem;                                     // 4096 B
  char* Vl   = smem + 4096;                              // 16384 B
  bf16* OlT  = reinterpret_cast<bf16*>(smem);            // 256*66*2 = 33792 B (post-loop)
  float* wo_s = reinterpret_cast<float*>(smem + 36864);  // 1024 B (post-loop)
  float* bo_s = reinterpret_cast<float*>(smem + 37888);  // 32 B
  const char* Pbase = Pattn + (size_t)bh*65536 + tb*4096;
  const char* Vbase = Vt + (size_t)bh*262144 + mb*16384;
  f32x4 acc[4][4];
#pragma unroll
  for (int i = 0; i < 4; i++)
#pragma unroll
    for (int j = 0; j < 4; j++) { f32x4 z = {0.f,0.f,0.f,0.f}; acc[i][j] = z; }
  for (int kb = 0; kb < 4; kb++) {
    __syncthreads();
    {
      const char* pc = Pbase + (size_t)kb*16384 + wave*1024 + lane*16;
      gload16(pc, Pl + wave*1024);
      const char* vc = Vbase + (size_t)kb*65536 + wave*4096 + lane*16;
      char* vl = Vl + wave*4096;
#pragma unroll
      for (int i = 0; i < 4; i++) gload16(vc + i*1024, vl + i*1024);
    }
    __syncthreads();
#pragma unroll
    for (int ks = 0; ks < 2; ks++) {
      int colx = (ks*32 + lg*8) ^ ((lr & 7) << 3);
      i64 a[4];
#pragma unroll
      for (int mi = 0; mi < 4; mi++)
        a[mi] = *reinterpret_cast<const i64*>(Pl + (mi*16 + lr)*64 + colx);
#pragma unroll
      for (int ni = 0; ni < 4; ni++) {
        i64 bfr = *reinterpret_cast<const i64*>(Vl + (wave*64 + ni*16 + lr)*64 + colx);
#pragma unroll
        for (int mi = 0; mi < 4; mi++)
          acc[mi][ni] = __builtin_amdgcn_mfma_f32_16x16x32_fp8_fp8(a[mi], bfr, acc[mi][ni], 0, 0, 0);
      }
    }
  }
  __syncthreads();   // all MFMA LDS reads done before OlT/wo_s overwrite
  const float rescale = 1.f/256.f;   // undo P*32 and V*8
#pragma unroll
  for (int mi = 0; mi < 4; mi++)
#pragma unroll
    for (int ni = 0; ni < 4; ni++) {
      int l = wave*64 + ni*16 + lr;
      int cb = mi*16 + lg*4;
      bf16x4 p;
      p[0] = (bf16)(acc[mi][ni][0]*rescale); p[1] = (bf16)(acc[mi][ni][1]*rescale);
      p[2] = (bf16)(acc[mi][ni][2]*rescale); p[3] = (bf16)(acc[mi][ni][3]*rescale);
      *reinterpret_cast<bf16x4*>(OlT + l*66 + cb) = p;
    }
  wo_s[t] = wo[((size_t)(h*32 + tb*8 + (t>>5)))*32 + (t & 31)];
  if (t < 8) bo_s[t] = bo[h*32 + tb*8 + t];
  __syncthreads();
  // epilogue: deconv 2x2 stride 2 + bias + residual; fully coalesced float4 I/O
  int xq = t & 15, b5 = (t >> 4) & 1, ct = t >> 5;
  float2 wp[8];
#pragma unroll
  for (int j = 0; j < 8; j++)
    wp[j] = *reinterpret_cast<const float2*>(wo_s + ct*32 + j*4 + (1 - b5)*2);
  float bias = bo_s[ct];
  float gm = gamma[0];
  int co = h*32 + tb*8 + ct;
#pragma unroll
  for (int it = 0; it < 8; it++) {
    int y = it*2 + b5;
    int ll0 = it*32 + xq*2;
    bf16x4 o00 = *reinterpret_cast<const bf16x4*>(OlT + ll0*66 + ct*8);
    bf16x4 o01 = *reinterpret_cast<const bf16x4*>(OlT + ll0*66 + ct*8 + 4);
    bf16x4 o10 = *reinterpret_cast<const bf16x4*>(OlT + (ll0+1)*66 + ct*8);
    bf16x4 o11 = *reinterpret_cast<const bf16x4*>(OlT + (ll0+1)*66 + ct*8 + 4);
    float v0 = bias, v1 = bias, v2 = bias, v3 = bias;
#pragma unroll
    for (int j = 0; j < 4; j++) {
      float f0 = (float)o00[j], f1 = (float)o01[j];
      v0 += f0*wp[j].y;   v1 += f0*wp[j].x;
      v0 += f1*wp[4+j].y; v1 += f1*wp[4+j].x;
      float g0 = (float)o10[j], g1 = (float)o11[j];
      v2 += g0*wp[j].y;   v3 += g0*wp[j].x;
      v2 += g1*wp[4+j].y; v3 += g1*wp[4+j].x;
    }
    size_t oi = (((size_t)b*256 + co)*64 + (mb*16 + y))*64 + xq*4;
    float4 qv = *reinterpret_cast<const float4*>(qin + oi);
    float4 ov;
    ov.x = qv.x + gm*v0; ov.y = qv.y + gm*v1;
    ov.z = qv.z + gm*v2; ov.w = qv.w + gm*v3;
    *reinterpret_cast<float4*>(outp + oi) = ov;
  }
}

extern "C" void kernel_launch(void* const* d_in, const int* in_sizes, int n_in,
                              void* d_out, int out_size, void* d_ws, size_t ws_size,
                              hipStream_t stream) {
  const float* q  = (const float*)d_in[0];
  const float* k  = (const float*)d_in[1];
  const float* v  = (const float*)d_in[2];
  const float* wq = (const float*)d_in[3];
  const float* bq = (const float*)d_in[4];
  const float* wk = (const float*)d_in[5];
  const float* bk = (const float*)d_in[6];
  const float* wv = (const float*)d_in[7];
  const float* bv = (const float*)d_in[8];
  const float* wo = (const float*)d_in[9];
  const float* bo = (const float*)d_in[10];
  const float* gamma = (const float*)d_in[11];
  float* out = (float*)d_out;

  char* ws = (char*)d_ws;
  char* Pk    = ws;                  //  16,777,216 B (fp8)
  char* Pq    = ws + 16777216;       //  16,777,216 B (fp8)
  char* Vt    = ws + 33554432;       //  16,777,216 B (fp8, x8)
  char* Pattn = ws + 50331648;       //   4,194,304 B (fp8, x32)

  proj_kqv<<<dim3(512, 8), 256, 0, stream>>>(k, q, v, wk, bk, wq, bq, wv, bv, Pk, Pq, Vt);
  attn_qk <<<dim3(256), 256, 0, stream>>>(Pq, Pk, Pattn);
  pv_deconv<<<dim3(1024), 256, 0, stream>>>(Pattn, Vt, q, wo, bo, gamma, out);
}

// Round 16
// 69.341 us; speedup vs baseline: 1.2886x; 1.0024x over previous
//
#include <hip/hip_runtime.h>
#include <hip/hip_bf16.h>

typedef __bf16 bf16;
typedef __bf16 bf16x4 __attribute__((ext_vector_type(4)));
typedef __bf16 bf16x8 __attribute__((ext_vector_type(8)));
typedef float f32x4 __attribute__((ext_vector_type(4)));
typedef long i64;

// async global->LDS, 16B per lane. LDS dest must be wave-uniform (HW adds lane*16).
__device__ __forceinline__ void gload16(const void* g, void* l) {
  __builtin_amdgcn_global_load_lds(
      (const __attribute__((address_space(1))) unsigned int*)g,
      (__attribute__((address_space(3))) unsigned int*)l, 16, 0, 0);
}

// All intermediates fp8 e4m3, 64-B rows, 8-B granules, granule-XOR (row&7):
//  Pq/Pk: [bh][kb16][row c(256)][64 B]   (k-dim l)   value = P
//  Vt:    [bh][db4] [row l(1024)][64 B]  (k-dim d)   value = 8*V
//  Pattn: [bh][db4] [row c(256)][64 B]   (k-dim d)   value = 32*P
// PV accumulator rescale: 1/(8*32) = 1/256.

// ---------------- Kernel A: projections. x<128: k-pair, x<256: q-pair, else v.
// k/q path: per-wave self-contained 4-stage half-channel pipeline, NO barriers.
// Wave stages rows [hi*32+wave*8, +8) of its channel half and computes exactly
// the kb's that read those rows. Counted vmcnt only: 2/4/4/2.
__global__ __launch_bounds__(256) void proj_kqv(
    const float* __restrict__ kin, const float* __restrict__ qin,
    const float* __restrict__ vin,
    const float* __restrict__ wk, const float* __restrict__ bk,
    const float* __restrict__ wq, const float* __restrict__ bq,
    const float* __restrict__ wv, const float* __restrict__ bv,
    char* __restrict__ Pk, char* __restrict__ Pq, char* __restrict__ Vt) {
  int b = blockIdx.y;
  int x = blockIdx.x;
  int t = threadIdx.x;
  int wave = t >> 6, lane = t & 63;
  __shared__ __attribute__((aligned(16))) char smem[17152];  // v: 32*2*67*4; k/q: 16384
  if (x < 256) {
    bool isq = x >= 128;
    int g0 = (x & 127)*2;
    const float* in   = isq ? qin : kin;
    const float* w    = isq ? wq : wk;
    const float* bias = isq ? bq : bk;
    char* out         = isq ? Pq : Pk;
    int j = (t >> 3) & 7, n = t & 7;
    // weights FIRST (4 vector loads; oldest in vmcnt FIFO)
    float4 wv0 = reinterpret_cast<const float4*>(w)[g0*8 + j];
    float  bb0 = bias[g0*8 + j];
    float4 wv1 = reinterpret_cast<const float4*>(w)[g0*8 + 8 + j];
    float  bb1 = bias[g0*8 + 8 + j];
    __builtin_amdgcn_sched_barrier(0);
    // half i: channel g0+(i>>1), rows (i&1)*32..+32. Wave stages its own 2KB slice.
    const char* src = (const char*)(in + ((size_t)b*256 + g0)*4096) + wave*2048 + lane*16;
    char* bw0 = smem + wave*2048;          // buffer 0, this wave's slice
    char* bw1 = smem + 8192 + wave*2048;   // buffer 1, this wave's slice
#define STAGEH(i, dst) { const char* s_ = src + ((i)>>1)*16384 + ((i)&1)*8192; \
    gload16(s_, dst); gload16(s_ + 1024, (dst) + 1024); }
    STAGEH(0, bw0);
    STAGEH(1, bw1);
    __builtin_amdgcn_sched_barrier(0);
    int h = g0 >> 5;                 // g0 even -> g0+1 shares h
    int bh = b*8 + h;
    int colb = (n & 3)*64;           // input col byte offset within 256-B row
    int rsel = 2*(n >> 2);           // row-pair select within kb

#define CONVH(i, bufwp, wvv, bj) { \
    int c0l = ((g0 + ((i)>>1)) & 31)*8; \
    _Pragma("unroll") \
    for (int pp = 0; pp < 2; pp++) { \
      int kb = ((i)&1)*8 + wave*2 + pp; \
      const char* R0p = (bufwp) + (pp*4 + rsel)*256 + colb; \
      float rr0[16], rr1[16]; \
      _Pragma("unroll") \
      for (int u = 0; u < 4; u++) { \
        *reinterpret_cast<float4*>(rr0 + u*4) = *reinterpret_cast<const float4*>(R0p + u*16); \
        *reinterpret_cast<float4*>(rr1 + u*4) = *reinterpret_cast<const float4*>(R0p + 256 + u*16); \
      } \
      float ov[8]; \
      _Pragma("unroll") \
      for (int u = 0; u < 8; u++) \
        ov[u] = (bj) + (wvv).x*rr0[2*u] + (wvv).y*rr0[2*u+1] + (wvv).z*rr1[2*u] + (wvv).w*rr1[2*u+1]; \
      int w0 = 0, w1 = 0; \
      w0 = __builtin_amdgcn_cvt_pk_fp8_f32(ov[0], ov[1], w0, false); \
      w0 = __builtin_amdgcn_cvt_pk_fp8_f32(ov[2], ov[3], w0, true); \
      w1 = __builtin_amdgcn_cvt_pk_fp8_f32(ov[4], ov[5], w1, false); \
      w1 = __builtin_amdgcn_cvt_pk_fp8_f32(ov[6], ov[7], w1, true); \
      size_t off = (((size_t)bh*16 + kb)*256 + c0l + j)*64 + (size_t)((n ^ j)*8); \
      int2 st; st.x = w0; st.y = w1; \
      *reinterpret_cast<int2*>(out + off) = st; \
    } }

    asm volatile("s_waitcnt vmcnt(2)" ::: "memory");   // weights + H0 landed (H1 in flight)
    CONVH(0, bw0, wv0, bb0);
    asm volatile("s_waitcnt lgkmcnt(0)" ::: "memory"); // all H0 ds_reads retired
    __builtin_amdgcn_sched_barrier(0);
    STAGEH(2, bw0);                                    // ch1 lower half over H0
    __builtin_amdgcn_sched_barrier(0);
    asm volatile("s_waitcnt vmcnt(4)" ::: "memory");   // H1 landed (S0 + H2 in flight)
    CONVH(1, bw1, wv0, bb0);
    asm volatile("s_waitcnt lgkmcnt(0)" ::: "memory");
    __builtin_amdgcn_sched_barrier(0);
    STAGEH(3, bw1);                                    // ch1 upper half over H1
    __builtin_amdgcn_sched_barrier(0);
    asm volatile("s_waitcnt vmcnt(4)" ::: "memory");   // H2 landed (S1 + H3 in flight)
    CONVH(2, bw0, wv1, bb1);
    asm volatile("s_waitcnt vmcnt(2)" ::: "memory");   // H3 landed (S2 in flight)
    CONVH(3, bw1, wv1, bb1);
#undef CONVH
#undef STAGEH
  } else {
    // ---- v projection into swizzled chunk-transposed Vt (fp8, x8 scale)
    float* ch = reinterpret_cast<float*>(smem);
    int r = x - 256;
    int m = r & 31, h = r >> 5;
    {
      int seg = t >> 2, part = t & 3;
      int gl = seg >> 1, ky = seg & 1;
      const float* src = vin + (((size_t)b*256 + h*32 + gl)*64 + (2*m + ky))*64;
      float* drow = ch + (gl*2 + ky)*67;
#pragma unroll
      for (int i = 0; i < 4; i++) {
        float4 v = reinterpret_cast<const float4*>(src)[part + i*4];
        int x0 = (part + i*4)*4;
        drow[x0]=v.x; drow[x0+1]=v.y; drow[x0+2]=v.z; drow[x0+3]=v.w;
      }
    }
    int cgrp = t & 31, lgr = t >> 5;
    int c0 = cgrp*8;
    float4 wv8[8]; float bb8[8];
#pragma unroll
    for (int u = 0; u < 8; u++) {
      wv8[u] = reinterpret_cast<const float4*>(wv)[h*256 + c0 + u];
      bb8[u] = bv[h*256 + c0 + u];
    }
    __syncthreads();
    const float* r0 = ch + (cgrp*2 + 0)*67;
    const float* r1 = ch + (cgrp*2 + 1)*67;
    int bh = b*8 + h;
    char* base = Vt + ((size_t)bh*4 + (c0 >> 6))*65536;
    int gsw = ((cgrp & 7) ^ lgr)*8;
#pragma unroll
    for (int p = 0; p < 4; p++) {
      int n = p*8 + lgr;
      int l = m*32 + n;               // l&7 == lgr
      float c00 = r0[2*n], c01 = r0[2*n+1], c10 = r1[2*n], c11 = r1[2*n+1];
      float ov[8];
#pragma unroll
      for (int u = 0; u < 8; u++)
        ov[u] = 8.f*(bb8[u] + wv8[u].x*c00 + wv8[u].y*c01 + wv8[u].z*c10 + wv8[u].w*c11);
      int w0 = 0, w1 = 0;
      w0 = __builtin_amdgcn_cvt_pk_fp8_f32(ov[0], ov[1], w0, false);
      w0 = __builtin_amdgcn_cvt_pk_fp8_f32(ov[2], ov[3], w0, true);
      w1 = __builtin_amdgcn_cvt_pk_fp8_f32(ov[4], ov[5], w1, false);
      w1 = __builtin_amdgcn_cvt_pk_fp8_f32(ov[6], ov[7], w1, true);
      int2 st; st.x = w0; st.y = w1;
      *reinterpret_cast<int2*>(base + (size_t)l*64 + gsw) = st;
    }
  }
}

// ---------------- Kernel B: S = Q K^T (fp8 MFMA) + softmax -> Pattn (fp8 x32).
__global__ __launch_bounds__(256, 2) void attn_qk(
    const char* __restrict__ Pq, const char* __restrict__ Pk,
    char* __restrict__ Pattn) {
  int raw = blockIdx.x;
  int idx = raw >> 3;
  int bh = (raw & 7)*8 + (idx >> 2);   // 4 c-strips of one bh share an XCD
  int cs = idx & 3;
  int t = threadIdx.x, wave = t >> 6, lane = t & 63, lg = lane >> 4, lr = lane & 15;
  __shared__ __attribute__((aligned(16))) char smem[40960];
  char* Kb0 = smem;                    // 16 KB
  char* Kb1 = smem + 16384;            // 16 KB
  char* Qb0 = smem + 32768;            //  4 KB
  char* Qb1 = smem + 36864;            //  4 KB
  float (*red)[64] = reinterpret_cast<float (*)[64]>(smem + 32768);  // post-loop alias
  char* Pst = smem;                    // 16 KB post-loop alias
  const char* Kbase = Pk + (size_t)bh*262144 + wave*4096 + lane*16;
  const char* Qbase = Pq + (size_t)bh*262144 + (size_t)cs*4096 + wave*1024 + lane*16;
  char* Kd0 = Kb0 + wave*4096;  char* Kd1 = Kb1 + wave*4096;
  char* Qd0 = Qb0 + wave*1024;  char* Qd1 = Qb1 + wave*1024;

#define STAGE(kb, K_, Q_) { \
    const char* kc = Kbase + (size_t)(kb)*16384; \
    _Pragma("unroll") \
    for (int i_ = 0; i_ < 4; i_++) gload16(kc + i_*1024, (K_) + i_*1024); \
    gload16(Qbase + (size_t)(kb)*16384, (Q_)); }

  f32x4 acc[4][4];
#pragma unroll
  for (int i = 0; i < 4; i++)
#pragma unroll
    for (int j = 0; j < 4; j++) { f32x4 z = {0.f,0.f,0.f,0.f}; acc[i][j] = z; }

  STAGE(0, Kd0, Qd0);
#pragma unroll
  for (int kb = 0; kb < 16; kb++) {
    if (kb < 15) {
      if (kb & 1) { STAGE(kb+1, Kd0, Qd0); } else { STAGE(kb+1, Kd1, Qd1); }
      asm volatile("s_waitcnt vmcnt(5)" ::: "memory");   // prev chunk complete
    } else {
      asm volatile("s_waitcnt vmcnt(0)" ::: "memory");
    }
    __builtin_amdgcn_s_barrier();
    __builtin_amdgcn_sched_barrier(0);
    const char* Kc = (kb & 1) ? Kb1 : Kb0;
    const char* Qc = (kb & 1) ? Qb1 : Qb0;
#pragma unroll
    for (int ks = 0; ks < 2; ks++) {
      int colx = (ks*32 + lg*8) ^ ((lr & 7) << 3);
      i64 a[4];
#pragma unroll
      for (int mi = 0; mi < 4; mi++)
        a[mi] = *reinterpret_cast<const i64*>(Qc + (mi*16 + lr)*64 + colx);
#pragma unroll
      for (int ni = 0; ni < 4; ni++) {
        i64 bfr = *reinterpret_cast<const i64*>(Kc + (wave*64 + ni*16 + lr)*64 + colx);
#pragma unroll
        for (int mi = 0; mi < 4; mi++)
          acc[mi][ni] = __builtin_amdgcn_mfma_f32_16x16x32_fp8_fp8(a[mi], bfr, acc[mi][ni], 0, 0, 0);
      }
    }
    __builtin_amdgcn_s_barrier();        // all reads of this buffer done
    __builtin_amdgcn_sched_barrier(0);
  }
#undef STAGE
  // softmax over d (wave holds 64 d; combine 4 waves via red[4][64])
  const float scale = 0.03125f;
  float sums[4][4];
#pragma unroll
  for (int mi = 0; mi < 4; mi++)
#pragma unroll
    for (int r = 0; r < 4; r++) {
      float mx = fmaxf(fmaxf(acc[mi][0][r], acc[mi][1][r]), fmaxf(acc[mi][2][r], acc[mi][3][r]));
#pragma unroll
      for (int off = 1; off < 16; off <<= 1) mx = fmaxf(mx, __shfl_xor(mx, off, 64));
      red[wave][mi*16 + lg*4 + r] = mx;
    }
  __syncthreads();
#pragma unroll
  for (int mi = 0; mi < 4; mi++)
#pragma unroll
    for (int r = 0; r < 4; r++) {
      int clr = mi*16 + lg*4 + r;
      float mx = fmaxf(fmaxf(red[0][clr], red[1][clr]), fmaxf(red[2][clr], red[3][clr]));
      float s = 0.f;
#pragma unroll
      for (int ni = 0; ni < 4; ni++) {
        float p = __expf(scale*(acc[mi][ni][r] - mx));
        acc[mi][ni][r] = p; s += p;
      }
#pragma unroll
      for (int off = 1; off < 16; off <<= 1) s += __shfl_xor(s, off, 64);
      sums[mi][r] = s;
    }
  __syncthreads();
#pragma unroll
  for (int mi = 0; mi < 4; mi++)
#pragma unroll
    for (int r = 0; r < 4; r++) red[wave][mi*16 + lg*4 + r] = sums[mi][r];
  __syncthreads();
  // normalize (x32) + stage P strip into LDS as fp8, swizzled layout
#pragma unroll
  for (int mi = 0; mi < 4; mi++)
#pragma unroll
    for (int r = 0; r < 4; r++) {
      int clr = mi*16 + lg*4 + r;
      float iv = 32.f/(red[0][clr] + red[1][clr] + red[2][clr] + red[3][clr]);
      char* prow = Pst + wave*4096 + clr*64;
      int xr = (clr & 7) << 3;
#pragma unroll
      for (int ni = 0; ni < 4; ni += 2) {
        int pk2 = __builtin_amdgcn_cvt_pk_fp8_f32(acc[mi][ni][r]*iv, acc[mi][ni+1][r]*iv, 0, false);
        prow[(ni*16 + lr) ^ xr]     = (char)(pk2 & 0xff);
        prow[((ni+1)*16 + lr) ^ xr] = (char)((pk2 >> 8) & 0xff);
      }
    }
  __syncthreads();
  // coalesced copy-out: 16 KB total; Pattn chunk kb gets rows cs*64..+64
  const uint4* ls = reinterpret_cast<const uint4*>(Pst);
#pragma unroll
  for (int i = 0; i < 4; i++) {
    int f = i*256 + t;              // 1024 uint4
    int kb = f >> 8, rem = f & 255;
    char* dst = Pattn + ((size_t)(bh*4 + kb)*256 + cs*64)*64 + (size_t)rem*16;
    *reinterpret_cast<uint4*>(dst) = ls[f];
  }
}

// ---------------- Kernel C: O = Pattn * V (fp8 MFMA), fused deconv + residual
__global__ __launch_bounds__(256, 4) void pv_deconv(const char* __restrict__ Pattn,
    const char* __restrict__ Vt, const float* __restrict__ qin,
    const float* __restrict__ wo, const float* __restrict__ bo,
    const float* __restrict__ gamma, float* __restrict__ outp) {
  int raw = blockIdx.x;
  int idx = raw >> 3;
  int pair = (raw & 7)*32 + (idx >> 2);   // (mb,bh); 4 tb-blocks share V chunk + XCD
  int tb = idx & 3;
  int mb = pair & 3, bh = pair >> 2;
  int h = bh & 7, b = bh >> 3;
  int t = threadIdx.x, wave = t >> 6, lane = t & 63, lg = lane >> 4, lr = lane & 15;
  __shared__ __attribute__((aligned(16))) char smem[40960];
  char* Pl   = smem;                                     // 4096 B
  char* Vl   = smem + 4096;                              // 16384 B
  bf16* OlT  = reinterpret_cast<bf16*>(smem);            // 256*66*2 = 33792 B (post-loop)
  float* wo_s = reinterpret_cast<float*>(smem + 36864);  // 1024 B (post-loop)
  float* bo_s = reinterpret_cast<float*>(smem + 37888);  // 32 B
  const char* Pbase = Pattn + (size_t)bh*65536 + tb*4096;
  const char* Vbase = Vt + (size_t)bh*262144 + mb*16384;
  f32x4 acc[4][4];
#pragma unroll
  for (int i = 0; i < 4; i++)
#pragma unroll
    for (int j = 0; j < 4; j++) { f32x4 z = {0.f,0.f,0.f,0.f}; acc[i][j] = z; }
  for (int kb = 0; kb < 4; kb++) {
    __syncthreads();
    {
      const char* pc = Pbase + (size_t)kb*16384 + wave*1024 + lane*16;
      gload16(pc, Pl + wave*1024);
      const char* vc = Vbase + (size_t)kb*65536 + wave*4096 + lane*16;
      char* vl = Vl + wave*4096;
#pragma unroll
      for (int i = 0; i < 4; i++) gload16(vc + i*1024, vl + i*1024);
    }
    __syncthreads();
#pragma unroll
    for (int ks = 0; ks < 2; ks++) {
      int colx = (ks*32 + lg*8) ^ ((lr & 7) << 3);
      i64 a[4];
#pragma unroll
      for (int mi = 0; mi < 4; mi++)
        a[mi] = *reinterpret_cast<const i64*>(Pl + (mi*16 + lr)*64 + colx);
#pragma unroll
      for (int ni = 0; ni < 4; ni++) {
        i64 bfr = *reinterpret_cast<const i64*>(Vl + (wave*64 + ni*16 + lr)*64 + colx);
#pragma unroll
        for (int mi = 0; mi < 4; mi++)
          acc[mi][ni] = __builtin_amdgcn_mfma_f32_16x16x32_fp8_fp8(a[mi], bfr, acc[mi][ni], 0, 0, 0);
      }
    }
  }
  __syncthreads();   // all MFMA LDS reads done before OlT/wo_s overwrite
  const float rescale = 1.f/256.f;   // undo P*32 and V*8
#pragma unroll
  for (int mi = 0; mi < 4; mi++)
#pragma unroll
    for (int ni = 0; ni < 4; ni++) {
      int l = wave*64 + ni*16 + lr;
      int cb = mi*16 + lg*4;
      bf16x4 p;
      p[0] = (bf16)(acc[mi][ni][0]*rescale); p[1] = (bf16)(acc[mi][ni][1]*rescale);
      p[2] = (bf16)(acc[mi][ni][2]*rescale); p[3] = (bf16)(acc[mi][ni][3]*rescale);
      *reinterpret_cast<bf16x4*>(OlT + l*66 + cb) = p;
    }
  wo_s[t] = wo[((size_t)(h*32 + tb*8 + (t>>5)))*32 + (t & 31)];
  if (t < 8) bo_s[t] = bo[h*32 + tb*8 + t];
  __syncthreads();
  // epilogue: deconv 2x2 stride 2 + bias + residual; fully coalesced float4 I/O
  int xq = t & 15, b5 = (t >> 4) & 1, ct = t >> 5;
  float2 wp[8];
#pragma unroll
  for (int j = 0; j < 8; j++)
    wp[j] = *reinterpret_cast<const float2*>(wo_s + ct*32 + j*4 + (1 - b5)*2);
  float bias = bo_s[ct];
  float gm = gamma[0];
  int co = h*32 + tb*8 + ct;
#pragma unroll
  for (int it = 0; it < 8; it++) {
    int y = it*2 + b5;
    int ll0 = it*32 + xq*2;
    bf16x4 o00 = *reinterpret_cast<const bf16x4*>(OlT + ll0*66 + ct*8);
    bf16x4 o01 = *reinterpret_cast<const bf16x4*>(OlT + ll0*66 + ct*8 + 4);
    bf16x4 o10 = *reinterpret_cast<const bf16x4*>(OlT + (ll0+1)*66 + ct*8);
    bf16x4 o11 = *reinterpret_cast<const bf16x4*>(OlT + (ll0+1)*66 + ct*8 + 4);
    float v0 = bias, v1 = bias, v2 = bias, v3 = bias;
#pragma unroll
    for (int j = 0; j < 4; j++) {
      float f0 = (float)o00[j], f1 = (float)o01[j];
      v0 += f0*wp[j].y;   v1 += f0*wp[j].x;
      v0 += f1*wp[4+j].y; v1 += f1*wp[4+j].x;
      float g0 = (float)o10[j], g1 = (float)o11[j];
      v2 += g0*wp[j].y;   v3 += g0*wp[j].x;
      v2 += g1*wp[4+j].y; v3 += g1*wp[4+j].x;
    }
    size_t oi = (((size_t)b*256 + co)*64 + (mb*16 + y))*64 + xq*4;
    float4 qv = *reinterpret_cast<const float4*>(qin + oi);
    float4 ov;
    ov.x = qv.x + gm*v0; ov.y = qv.y + gm*v1;
    ov.z = qv.z + gm*v2; ov.w = qv.w + gm*v3;
    *reinterpret_cast<float4*>(outp + oi) = ov;
  }
}

extern "C" void kernel_launch(void* const* d_in, const int* in_sizes, int n_in,
                              void* d_out, int out_size, void* d_ws, size_t ws_size,
                              hipStream_t stream) {
  const float* q  = (const float*)d_in[0];
  const float* k  = (const float*)d_in[1];
  const float* v  = (const float*)d_in[2];
  const float* wq = (const float*)d_in[3];
  const float* bq = (const float*)d_in[4];
  const float* wk = (const float*)d_in[5];
  const float* bk = (const float*)d_in[6];
  const float* wv = (const float*)d_in[7];
  const float* bv = (const float*)d_in[8];
  const float* wo = (const float*)d_in[9];
  const float* bo = (const float*)d_in[10];
  const float* gamma = (const float*)d_in[11];
  float* out = (float*)d_out;

  char* ws = (char*)d_ws;
  char* Pk    = ws;                  //  16,777,216 B (fp8)
  char* Pq    = ws + 16777216;       //  16,777,216 B (fp8)
  char* Vt    = ws + 33554432;       //  16,777,216 B (fp8, x8)
  char* Pattn = ws + 50331648;       //   4,194,304 B (fp8, x32)

  proj_kqv<<<dim3(512, 8), 256, 0, stream>>>(k, q, v, wk, bk, wq, bq, wv, bv, Pk, Pq, Vt);
  attn_qk <<<dim3(256), 256, 0, stream>>>(Pq, Pk, Pattn);
  pv_deconv<<<dim3(1024), 256, 0, stream>>>(Pattn, Vt, q, wo, bo, gamma, out);
}